// Round 1
// baseline (1421.420 us; speedup 1.0000x reference)
//
#include <hip/hip_runtime.h>
#include <hip/hip_bf16.h>

#define ELq 4194304   // B*T*C
#define Cq 2048
#define Tq 1024
#define Hq 32
#define Mq 2048       // B*T

typedef __attribute__((ext_vector_type(8))) short bf16x8;
typedef __attribute__((ext_vector_type(4))) float f32x4;

__device__ __forceinline__ unsigned short f2bu(float f) {
  union { float f; unsigned u; } v; v.f = f;
  unsigned r = v.u + 0x7fffu + ((v.u >> 16) & 1u);
  return (unsigned short)(r >> 16);
}
__device__ __forceinline__ float b2f(unsigned short u) {
  union { unsigned u; float f; } v; v.u = ((unsigned)u) << 16;
  return v.f;
}
__device__ __forceinline__ void gl_lds16(const void* g, void* l) {
  __builtin_amdgcn_global_load_lds((const __attribute__((address_space(1))) unsigned int*)g,
                                   (__attribute__((address_space(3))) unsigned int*)l, 16, 0, 0);
}
__device__ __forceinline__ void gl_lds4(const void* g, void* l) {
  __builtin_amdgcn_global_load_lds((const __attribute__((address_space(1))) unsigned int*)g,
                                   (__attribute__((address_space(3))) unsigned int*)l, 4, 0, 0);
}

// ---------------- weight convert / transpose ----------------
struct ConvJob { const float* src; unsigned short* dst; int rows, cols, trans; };
struct ConvJobs { ConvJob j[12]; };

__global__ void k_conv(ConvJobs jobs) {
  ConvJob jb = jobs.j[blockIdx.z];
  int n = jb.rows * jb.cols;
  for (int i = blockIdx.x * blockDim.x + threadIdx.x; i < n; i += gridDim.x * blockDim.x) {
    float v;
    if (jb.trans) {
      int col = i / jb.rows;            // out (cols, rows): out[col][row] = in[row][col]
      int row = i - col * jb.rows;
      v = jb.src[(size_t)row * jb.cols + col];
    } else {
      v = jb.src[i];
    }
    jb.dst[i] = f2bu(v);
  }
}

__global__ void k_zero(unsigned int* p) { if (threadIdx.x < 8) p[threadIdx.x] = 0u; }

// ---------------- token shift prologue ----------------
__global__ void k_prologue(const float* __restrict__ x,
    const float* __restrict__ mr, const float* __restrict__ mw, const float* __restrict__ mk,
    const float* __restrict__ mv, const float* __restrict__ ma, const float* __restrict__ mg,
    unsigned short* __restrict__ xr, unsigned short* __restrict__ xw, unsigned short* __restrict__ xk,
    unsigned short* __restrict__ xv, unsigned short* __restrict__ xa, unsigned short* __restrict__ xg)
{
  int i = blockIdx.x * 256 + threadIdx.x;
  if (i >= ELq) return;
  float xc = x[i];
  int t = (i >> 11) & (Tq - 1);
  float xp = t ? x[i - Cq] : 0.f;
  float dx = xp - xc;
  int c = i & (Cq - 1);
  xr[i] = f2bu(xc + dx * mr[c]);
  xw[i] = f2bu(xc + dx * mw[c]);
  xk[i] = f2bu(xc + dx * mk[c]);
  xv[i] = f2bu(xc + dx * mv[c]);
  xa[i] = f2bu(xc + dx * ma[c]);
  xg[i] = f2bu(xc + dx * mg[c]);
}

// ---------------- GEMM (A MxK row-major bf16, B NxK row-major bf16; C = A*B^T) ----------------
struct GJob {
  const unsigned short* A; const unsigned short* B;
  const float* bias; float* Cf; unsigned short* Cb;
  unsigned int* amax; const unsigned int* flag;
  int K; int epi;
};
struct GJobs { GJob j[4]; };

// epi: 0 f32 | 1 f32+bias | 2 f32 sigmoid(v+bias) | 3 bf16 tanh | 4 bf16 | 5 bf16 sigmoid
//      6 bf16+absmax | 7 f32+absmax | 8 f32*flagscale
__device__ __forceinline__ void epi_store(int epi, float v, size_t o,
    float* Cf, unsigned short* Cb, const float* bias, int col, float scale, float& lmax)
{
  switch (epi) {
    case 0: Cf[o] = v; break;
    case 1: Cf[o] = v + bias[col]; break;
    case 2: Cf[o] = 1.f / (1.f + expf(-(v + bias[col]))); break;
    case 3: Cb[o] = f2bu(tanhf(v)); break;
    case 4: Cb[o] = f2bu(v); break;
    case 5: Cb[o] = f2bu(1.f / (1.f + expf(-v))); break;
    case 6: lmax = fmaxf(lmax, fabsf(v)); Cb[o] = f2bu(v); break;
    case 7: lmax = fmaxf(lmax, fabsf(v)); Cf[o] = v; break;
    case 8: Cf[o] = v * scale; break;
  }
}

__global__ __launch_bounds__(256, 2) void k_gemm128(GJobs jobs) {
  GJob jb = jobs.j[blockIdx.z];
  __shared__ __align__(16) unsigned short As[128 * 32];
  __shared__ __align__(16) unsigned short Bs[128 * 32];
  __shared__ float sred[4];
  const int tid = threadIdx.x, lane = tid & 63, wid = tid >> 6;
  const int wr = wid >> 1, wc = wid & 1;
  const int m0 = blockIdx.y * 128, n0 = blockIdx.x * 128;
  const int K = jb.K;
  const unsigned short* A = jb.A; const unsigned short* B = jb.B;
  f32x4 acc[4][4] = {};
  for (int k0 = 0; k0 < K; k0 += 32) {
    #pragma unroll
    for (int i = 0; i < 2; ++i) {
      int cw = wid * 64 + i * 256;   // wave-uniform chunk base
      int c = cw + lane;
      int row = c >> 2, q = c & 3;
      gl_lds16(A + (size_t)(m0 + row) * K + k0 + q * 8, &As[cw * 8]);
      gl_lds16(B + (size_t)(n0 + row) * K + k0 + q * 8, &Bs[cw * 8]);
    }
    __syncthreads();
    const int kg = (lane >> 4) * 8;
    bf16x8 af[4], bq[4];
    #pragma unroll
    for (int mi = 0; mi < 4; ++mi)
      af[mi] = *(const bf16x8*)&As[(wr * 64 + mi * 16 + (lane & 15)) * 32 + kg];
    #pragma unroll
    for (int ni = 0; ni < 4; ++ni)
      bq[ni] = *(const bf16x8*)&Bs[(wc * 64 + ni * 16 + (lane & 15)) * 32 + kg];
    #pragma unroll
    for (int mi = 0; mi < 4; ++mi)
      #pragma unroll
      for (int ni = 0; ni < 4; ++ni)
        acc[mi][ni] = __builtin_amdgcn_mfma_f32_16x16x32_bf16(af[mi], bq[ni], acc[mi][ni], 0, 0, 0);
    __syncthreads();
  }
  float scale = 1.f;
  if (jb.epi == 8) scale = (__uint_as_float(*jb.flag) > 179.2f) ? 0.5f : 1.f;
  float lmax = 0.f;
  #pragma unroll
  for (int mi = 0; mi < 4; ++mi)
    #pragma unroll
    for (int ni = 0; ni < 4; ++ni) {
      int col = n0 + wc * 64 + ni * 16 + (lane & 15);
      int row = m0 + wr * 64 + mi * 16 + ((lane >> 4) << 2);
      #pragma unroll
      for (int q = 0; q < 4; ++q)
        epi_store(jb.epi, acc[mi][ni][q], (size_t)(row + q) * 2048 + col,
                  jb.Cf, jb.Cb, jb.bias, col, scale, lmax);
    }
  if (jb.epi == 6 || jb.epi == 7) {
    #pragma unroll
    for (int o = 32; o; o >>= 1) lmax = fmaxf(lmax, __shfl_xor(lmax, o));
    if (lane == 0) sred[wid] = lmax;
    __syncthreads();
    if (tid == 0)
      atomicMax(jb.amax, __float_as_uint(fmaxf(fmaxf(sred[0], sred[1]), fmaxf(sred[2], sred[3]))));
  }
}

template<int TBN>
__global__ __launch_bounds__(256, 2) void k_gemmN(GJob jb) {
  __shared__ __align__(16) unsigned short As[128 * 32];
  __shared__ __align__(16) unsigned short Bs[TBN * 32];
  __shared__ float sred[4];
  const int tid = threadIdx.x, lane = tid & 63, wid = tid >> 6;
  const int m0 = blockIdx.x * 128;
  const int K = jb.K;
  constexpr int NF = TBN / 16;
  const unsigned short* A = jb.A; const unsigned short* B = jb.B;
  f32x4 acc[2][NF] = {};
  for (int k0 = 0; k0 < K; k0 += 32) {
    for (int cw = wid * 64; cw < 512; cw += 256) {
      int c = cw + lane; int row = c >> 2, q = c & 3;
      gl_lds16(A + (size_t)(m0 + row) * K + k0 + q * 8, &As[cw * 8]);
    }
    for (int cw = wid * 64; cw < TBN * 4; cw += 256) {
      int c = cw + lane; int row = c >> 2, q = c & 3;
      gl_lds16(B + (size_t)row * K + k0 + q * 8, &Bs[cw * 8]);
    }
    __syncthreads();
    const int kg = (lane >> 4) * 8;
    bf16x8 af[2], bq[NF];
    #pragma unroll
    for (int mi = 0; mi < 2; ++mi)
      af[mi] = *(const bf16x8*)&As[(wid * 32 + mi * 16 + (lane & 15)) * 32 + kg];
    #pragma unroll
    for (int ni = 0; ni < NF; ++ni)
      bq[ni] = *(const bf16x8*)&Bs[(ni * 16 + (lane & 15)) * 32 + kg];
    #pragma unroll
    for (int mi = 0; mi < 2; ++mi)
      #pragma unroll
      for (int ni = 0; ni < NF; ++ni)
        acc[mi][ni] = __builtin_amdgcn_mfma_f32_16x16x32_bf16(af[mi], bq[ni], acc[mi][ni], 0, 0, 0);
    __syncthreads();
  }
  float lmax = 0.f;
  #pragma unroll
  for (int mi = 0; mi < 2; ++mi)
    #pragma unroll
    for (int ni = 0; ni < NF; ++ni) {
      int col = ni * 16 + (lane & 15);
      int row = m0 + wid * 32 + mi * 16 + ((lane >> 4) << 2);
      #pragma unroll
      for (int q = 0; q < 4; ++q)
        epi_store(jb.epi, acc[mi][ni][q], (size_t)(row + q) * TBN + col,
                  jb.Cf, jb.Cb, jb.bias, col, 1.f, lmax);
    }
  if (jb.epi == 6 || jb.epi == 7) {
    #pragma unroll
    for (int o = 32; o; o >>= 1) lmax = fmaxf(lmax, __shfl_xor(lmax, o));
    if (lane == 0) sred[wid] = lmax;
    __syncthreads();
    if (tid == 0)
      atomicMax(jb.amax, __float_as_uint(fmaxf(fmaxf(sred[0], sred[1]), fmaxf(sred[2], sred[3]))));
  }
}

// ---------------- absmax(v_first - v_raw) ----------------
__global__ void k_absmax_diff(const float* __restrict__ a, const float* __restrict__ b, unsigned int* out) {
  float m = 0.f;
  for (int i = blockIdx.x * blockDim.x + threadIdx.x; i < ELq; i += gridDim.x * blockDim.x)
    m = fmaxf(m, fabsf(a[i] - b[i]));
  #pragma unroll
  for (int o = 32; o; o >>= 1) m = fmaxf(m, __shfl_xor(m, o));
  __shared__ float sred[4];
  int lane = threadIdx.x & 63, wid = threadIdx.x >> 6;
  if (lane == 0) sred[wid] = m;
  __syncthreads();
  if (threadIdx.x == 0)
    atomicMax(out, __float_as_uint(fmaxf(fmaxf(sred[0], sred[1]), fmaxf(sred[2], sred[3]))));
}

// ---------------- v residual gating (in place over v_raw) ----------------
__global__ void k_vfin(float* __restrict__ v, const float* __restrict__ vf, const float* __restrict__ z,
                       const float* __restrict__ v0, const unsigned int* __restrict__ sc) {
  int i = blockIdx.x * 256 + threadIdx.x;
  if (i >= ELq) return;
  float m1 = fmaxf(__uint_as_float(sc[0]), 1.f);
  float m2 = fmaxf(__uint_as_float(sc[1]) / m1, 1.f);
  float mvd = fmaxf(__uint_as_float(sc[2]), 1.f);
  int c = i & (Cq - 1);
  float gx = v0[c] + z[i] / (m1 * m2);
  gx = fminf(fmaxf(gx, -16.f), 16.f);
  float gate = 1.f / (1.f + expf(-gx));
  float vr = v[i];
  v[i] = vr + (vf[i] - vr) * (gate / mvd);
}

// ---------------- wkv stream prep: kk-norm, k-final, decay, a/b streams ----------------
__global__ __launch_bounds__(256) void k_prep(float* __restrict__ k, float* __restrict__ w,
    float* __restrict__ asig, float* __restrict__ kkout,
    const float* __restrict__ kkw, const float* __restrict__ kaw) {
  int wid = threadIdx.x >> 6, lane = threadIdx.x & 63;
  int idx = blockIdx.x * 4 + wid;          // (b*T + t)*H + h
  size_t off = (size_t)idx * 64 + lane;
  int c = ((idx & (Hq - 1)) << 6) | lane;  // h*64 + n
  float kr = k[off];
  float kkv = kr * kkw[c];
  float ss = kkv * kkv;
  #pragma unroll
  for (int o = 32; o; o >>= 1) ss += __shfl_xor(ss, o);
  float kkn = kkv / fmaxf(sqrtf(ss), 1e-12f);
  float as = asig[off];
  kkout[off] = -kkn;                       // a-stream
  asig[off] = kkn * as;                    // b-stream (overwrite after read)
  k[off] = kr * (1.f + (as - 1.f) * kaw[c]);
  float wl = w[off];
  float wlog = -log1pf(expf(-wl)) - 0.5f;  // -softplus(-wlog) - 0.5
  w[off] = expf(-expf(wlog));              // decay in (0,1)
}

// ---------------- wkv7 scan: 1 block per (b,h), 4 waves split 64 columns ----------------
__global__ __launch_bounds__(256) void k_wkv(
    const float* __restrict__ rS, const float* __restrict__ wS, const float* __restrict__ kS,
    const float* __restrict__ vS, const float* __restrict__ aS, const float* __restrict__ bS,
    float* __restrict__ y, unsigned int* __restrict__ ymax) {
  const int bh = blockIdx.x;
  const int lane = threadIdx.x & 63, wv = threadIdx.x >> 6;
  __shared__ __align__(16) float Ls[2][6][64];   // streams r,w,k,v,a,b double-buffered
  __shared__ float red[4][68];
  __shared__ float yrd[4][68];
  float S[16];
  #pragma unroll
  for (int j = 0; j < 16; ++j) S[j] = 0.f;
  size_t base = (size_t)(bh >> 5) * Tq * Cq + (size_t)(bh & 31) * 64;
  const float* ptr0 = (wv == 0) ? rS : (wv == 1) ? wS : (wv == 2) ? kS : vS;
  const float* ptr1 = (wv == 0) ? aS : bS;
  gl_lds4(ptr0 + base + lane, &Ls[0][wv][0]);
  if (wv < 2) gl_lds4(ptr1 + base + lane, &Ls[0][4 + wv][0]);
  float ymx = 0.f;
  for (int t = 0; t < Tq; ++t) {
    const int cur = t & 1, nxt = cur ^ 1;
    __syncthreads();                       // staged[cur] visible (barrier drains vmcnt)
    size_t nb = (t < Tq - 1) ? base + Cq : base;
    gl_lds4(ptr0 + nb + lane, &Ls[nxt][wv][0]);
    if (wv < 2) gl_lds4(ptr1 + nb + lane, &Ls[nxt][4 + wv][0]);
    // phase 1: partial sa over this wave's 16 columns
    const float4* Ap = (const float4*)&Ls[cur][4][wv * 16];
    float4 a0 = Ap[0], a1 = Ap[1], a2 = Ap[2], a3 = Ap[3];
    float p0 = S[0]*a0.x + S[4]*a1.x + S[8]*a2.x  + S[12]*a3.x;
    float p1 = S[1]*a0.y + S[5]*a1.y + S[9]*a2.y  + S[13]*a3.y;
    float p2 = S[2]*a0.z + S[6]*a1.z + S[10]*a2.z + S[14]*a3.z;
    float p3 = S[3]*a0.w + S[7]*a1.w + S[11]*a2.w + S[15]*a3.w;
    red[wv][lane] = (p0 + p1) + (p2 + p3);
    __syncthreads();
    float sa = red[0][lane] + red[1][lane] + red[2][lane] + red[3][lane];
    // phase 2: state update + partial y
    float vi = Ls[cur][3][lane];
    const float4* Wp = (const float4*)&Ls[cur][1][wv * 16];
    const float4* Kp = (const float4*)&Ls[cur][2][wv * 16];
    const float4* Bp = (const float4*)&Ls[cur][5][wv * 16];
    const float4* Rp = (const float4*)&Ls[cur][0][wv * 16];
    float y0 = 0.f, y1 = 0.f, y2 = 0.f, y3 = 0.f;
    #pragma unroll
    for (int g4 = 0; g4 < 4; ++g4) {
      float4 w4 = Wp[g4], k4 = Kp[g4], b4 = Bp[g4], r4 = Rp[g4];
      float s0 = S[g4*4+0] * w4.x + (sa * b4.x + vi * k4.x);
      float s1 = S[g4*4+1] * w4.y + (sa * b4.y + vi * k4.y);
      float s2 = S[g4*4+2] * w4.z + (sa * b4.z + vi * k4.z);
      float s3 = S[g4*4+3] * w4.w + (sa * b4.w + vi * k4.w);
      S[g4*4+0] = s0; S[g4*4+1] = s1; S[g4*4+2] = s2; S[g4*4+3] = s3;
      y0 += s0 * r4.x; y1 += s1 * r4.y; y2 += s2 * r4.z; y3 += s3 * r4.w;
    }
    yrd[wv][lane] = (y0 + y1) + (y2 + y3);
    __syncthreads();
    if (wv == 0) {
      float yo = yrd[0][lane] + yrd[1][lane] + yrd[2][lane] + yrd[3][lane];
      y[base + lane] = yo;
      ymx = fmaxf(ymx, fabsf(yo));
    }
    base += Cq;
  }
  if (wv == 0) {
    #pragma unroll
    for (int o = 32; o; o >>= 1) ymx = fmaxf(ymx, __shfl_xor(ymx, o));
    if (lane == 0) atomicMax(ymax, __float_as_uint(ymx));
  }
}

// ---------------- groupnorm + bonus + gate ----------------
__global__ __launch_bounds__(256) void k_epi1(const float* __restrict__ y, const float* __restrict__ r,
    const float* __restrict__ k, const float* __restrict__ v, const unsigned short* __restrict__ g,
    const float* __restrict__ lnw, const float* __restrict__ lnb, const float* __restrict__ rk,
    unsigned short* __restrict__ yg) {
  int wid = threadIdx.x >> 6, lane = threadIdx.x & 63;
  int idx = blockIdx.x * 4 + wid;
  size_t off = (size_t)idx * 64 + lane;
  int c = ((idx & (Hq - 1)) << 6) | lane;
  float yv = y[off];
  float s = yv;
  #pragma unroll
  for (int o = 32; o; o >>= 1) s += __shfl_xor(s, o);
  float mu = s * (1.f / 64.f);
  float d = yv - mu;
  float vs = d * d;
  #pragma unroll
  for (int o = 32; o; o >>= 1) vs += __shfl_xor(vs, o);
  float yn = d / sqrtf(vs * (1.f / 64.f) + 6.4e-4f);
  float yo = yn * lnw[c] + lnb[c];
  float bon = r[off] * k[off] * rk[c];
  #pragma unroll
  for (int o = 32; o; o >>= 1) bon += __shfl_xor(bon, o);
  yo += bon * v[off];
  yg[off] = f2bu(yo * b2f(g[off]));
}

// ---------------- v_first output ----------------
__global__ void k_vout(const float* __restrict__ vf, const unsigned int* __restrict__ sc,
                       float* __restrict__ out) {
  int i = blockIdx.x * 256 + threadIdx.x;
  if (i >= ELq) return;
  float s = (__uint_as_float(sc[3]) > 179.2f) ? 0.5f : 1.f;
  out[i] = vf[i] * s;
}

extern "C" void kernel_launch(void* const* d_in, const int* in_sizes, int n_in,
                              void* d_out, int out_size, void* d_ws, size_t ws_size,
                              hipStream_t stream) {
  const float* x      = (const float*)d_in[0];
  const float* vfirst = (const float*)d_in[1];
  const float* x_r = (const float*)d_in[2];
  const float* x_w = (const float*)d_in[3];
  const float* x_k = (const float*)d_in[4];
  const float* x_v = (const float*)d_in[5];
  const float* x_a = (const float*)d_in[6];
  const float* x_g = (const float*)d_in[7];
  const float* w0 = (const float*)d_in[8];
  const float* w1 = (const float*)d_in[9];
  const float* w2 = (const float*)d_in[10];
  const float* a0 = (const float*)d_in[11];
  const float* a1 = (const float*)d_in[12];
  const float* a2 = (const float*)d_in[13];
  const float* v0 = (const float*)d_in[14];
  const float* v1 = (const float*)d_in[15];
  const float* v2 = (const float*)d_in[16];
  const float* g1 = (const float*)d_in[17];
  const float* g2 = (const float*)d_in[18];
  const float* k_k = (const float*)d_in[19];
  const float* k_a = (const float*)d_in[20];
  const float* r_k = (const float*)d_in[21];
  const float* W_r = (const float*)d_in[22];
  const float* W_k = (const float*)d_in[23];
  const float* W_v = (const float*)d_in[24];
  const float* W_o = (const float*)d_in[25];
  const float* lnw = (const float*)d_in[26];
  const float* lnb = (const float*)d_in[27];

  char* ws = (char*)d_ws;
  size_t off = 0;
  auto alloc = [&](size_t bytes) -> void* {
    void* p = ws + off; off += (bytes + 255) & ~(size_t)255; return p;
  };
  unsigned int* scal = (unsigned int*)alloc(256);      // [M1, MZ, MVD, MY]
  float* kbuf  = (float*)alloc((size_t)ELq * 4);
  float* vbuf  = (float*)alloc((size_t)ELq * 4);
  float* wbuf  = (float*)alloc((size_t)ELq * 4);
  float* abuf  = (float*)alloc((size_t)ELq * 4);
  float* kkbuf = (float*)alloc((size_t)ELq * 4);
  float* ybuf  = (float*)alloc((size_t)ELq * 4);
  unsigned short* xrb = (unsigned short*)alloc((size_t)ELq * 2);
  unsigned short* xwb = (unsigned short*)alloc((size_t)ELq * 2);
  unsigned short* xkb = (unsigned short*)alloc((size_t)ELq * 2);
  unsigned short* xvb = (unsigned short*)alloc((size_t)ELq * 2);
  unsigned short* xab = (unsigned short*)alloc((size_t)ELq * 2);
  unsigned short* xgb = (unsigned short*)alloc((size_t)ELq * 2);
  unsigned short* gbuf = (unsigned short*)alloc((size_t)ELq * 2);
  unsigned short* ygb  = (unsigned short*)alloc((size_t)ELq * 2);
  unsigned short* WrB = (unsigned short*)alloc((size_t)ELq * 2);
  unsigned short* WkB = (unsigned short*)alloc((size_t)ELq * 2);
  unsigned short* WvB = (unsigned short*)alloc((size_t)ELq * 2);
  unsigned short* WoB = (unsigned short*)alloc((size_t)ELq * 2);
  unsigned short* w1T = (unsigned short*)alloc(64 * 2048 * 2);
  unsigned short* a1T = (unsigned short*)alloc(64 * 2048 * 2);
  unsigned short* v1T = (unsigned short*)alloc(32 * 2048 * 2);
  unsigned short* g1T = (unsigned short*)alloc(128 * 2048 * 2);
  unsigned short* w2T = (unsigned short*)alloc(2048 * 64 * 2);
  unsigned short* a2T = (unsigned short*)alloc(2048 * 64 * 2);
  unsigned short* v2T = (unsigned short*)alloc(2048 * 32 * 2);
  unsigned short* g2T = (unsigned short*)alloc(2048 * 128 * 2);
  unsigned short* hwb = (unsigned short*)alloc((size_t)Mq * 64 * 2);
  unsigned short* hab = (unsigned short*)alloc((size_t)Mq * 64 * 2);
  unsigned short* hvb = (unsigned short*)alloc((size_t)Mq * 32 * 2);
  unsigned short* hgb = (unsigned short*)alloc((size_t)Mq * 128 * 2);
  // d_out doubles as scratch: r in first half (dead before final GEMM writes y there),
  // z in second half (dead before k_vout writes v_first_out there).
  float* rbuf = (float*)d_out;
  float* zbuf = (float*)d_out + ELq;
  float* yout = (float*)d_out;
  float* vfout = (float*)d_out + ELq;

  k_zero<<<1, 64, 0, stream>>>(scal);

  ConvJobs cj;
  cj.j[0]  = {W_r, WrB, Cq, Cq, 0};
  cj.j[1]  = {W_k, WkB, Cq, Cq, 0};
  cj.j[2]  = {W_v, WvB, Cq, Cq, 0};
  cj.j[3]  = {W_o, WoB, Cq, Cq, 0};
  cj.j[4]  = {w1, w1T, 2048, 64, 1};
  cj.j[5]  = {a1, a1T, 2048, 64, 1};
  cj.j[6]  = {v1, v1T, 2048, 32, 1};
  cj.j[7]  = {g1, g1T, 2048, 128, 1};
  cj.j[8]  = {w2, w2T, 64, 2048, 1};
  cj.j[9]  = {a2, a2T, 64, 2048, 1};
  cj.j[10] = {v2, v2T, 32, 2048, 1};
  cj.j[11] = {g2, g2T, 128, 2048, 1};
  k_conv<<<dim3(1024, 1, 12), 256, 0, stream>>>(cj);

  k_prologue<<<ELq / 256, 256, 0, stream>>>(x, x_r, x_w, x_k, x_v, x_a, x_g,
                                            xrb, xwb, xkb, xvb, xab, xgb);

  GJobs g1j;
  g1j.j[0] = {xrb, WrB, nullptr, rbuf, nullptr, nullptr, nullptr, 2048, 0};
  g1j.j[1] = {xkb, WkB, nullptr, kbuf, nullptr, nullptr, nullptr, 2048, 0};
  g1j.j[2] = {xvb, WvB, nullptr, vbuf, nullptr, nullptr, nullptr, 2048, 0};
  g1j.j[3] = g1j.j[0];
  k_gemm128<<<dim3(16, 16, 3), 256, 0, stream>>>(g1j);

  GJob jw = {xwb, w1T, nullptr, nullptr, hwb, nullptr, nullptr, 2048, 3};
  k_gemmN<64><<<16, 256, 0, stream>>>(jw);
  GJob ja = {xab, a1T, nullptr, nullptr, hab, nullptr, nullptr, 2048, 4};
  k_gemmN<64><<<16, 256, 0, stream>>>(ja);
  GJob jv = {xvb, v1T, nullptr, nullptr, hvb, scal + 0, nullptr, 2048, 6};
  k_gemmN<32><<<16, 256, 0, stream>>>(jv);
  GJob jg = {xgb, g1T, nullptr, nullptr, hgb, nullptr, nullptr, 2048, 5};
  k_gemmN<128><<<16, 256, 0, stream>>>(jg);

  GJobs g3j;
  g3j.j[0] = {hwb, w2T, w0, wbuf, nullptr, nullptr, nullptr, 64, 1};
  g3j.j[1] = {hab, a2T, a0, abuf, nullptr, nullptr, nullptr, 64, 2};
  g3j.j[2] = {hvb, v2T, nullptr, zbuf, nullptr, scal + 1, nullptr, 32, 7};
  g3j.j[3] = {hgb, g2T, nullptr, nullptr, gbuf, nullptr, nullptr, 128, 4};
  k_gemm128<<<dim3(16, 16, 4), 256, 0, stream>>>(g3j);

  k_absmax_diff<<<1024, 256, 0, stream>>>(vfirst, vbuf, scal + 2);
  k_vfin<<<ELq / 256, 256, 0, stream>>>(vbuf, vfirst, zbuf, v0, scal);
  k_prep<<<(2 * Tq * Hq) / 4, 256, 0, stream>>>(kbuf, wbuf, abuf, kkbuf, k_k, k_a);
  k_wkv<<<2 * Hq, 256, 0, stream>>>(rbuf, wbuf, kbuf, vbuf, kkbuf, abuf, ybuf, scal + 3);
  k_epi1<<<(2 * Tq * Hq) / 4, 256, 0, stream>>>(ybuf, rbuf, kbuf, vbuf, gbuf, lnw, lnb, r_k, ygb);

  GJobs gfj;
  gfj.j[0] = {ygb, WoB, nullptr, yout, nullptr, nullptr, scal + 3, 2048, 8};
  gfj.j[1] = gfj.j[0]; gfj.j[2] = gfj.j[0]; gfj.j[3] = gfj.j[0];
  k_gemm128<<<dim3(16, 16, 1), 256, 0, stream>>>(gfj);

  k_vout<<<ELq / 256, 256, 0, stream>>>(vfirst, scal, vfout);
}

// Round 2
// 1254.763 us; speedup vs baseline: 1.1328x; 1.1328x over previous
//
#include <hip/hip_runtime.h>
#include <hip/hip_bf16.h>

#define ELq 4194304   // B*T*C
#define Cq 2048
#define Tq 1024
#define Hq 32
#define Mq 2048       // B*T

typedef __attribute__((ext_vector_type(8))) short bf16x8;
typedef __attribute__((ext_vector_type(4))) float f32x4;

__device__ __forceinline__ unsigned short f2bu(float f) {
  union { float f; unsigned u; } v; v.f = f;
  unsigned r = v.u + 0x7fffu + ((v.u >> 16) & 1u);
  return (unsigned short)(r >> 16);
}
__device__ __forceinline__ float b2f(unsigned short u) {
  union { unsigned u; float f; } v; v.u = ((unsigned)u) << 16;
  return v.f;
}
__device__ __forceinline__ void gl_lds16(const void* g, void* l) {
  __builtin_amdgcn_global_load_lds((const __attribute__((address_space(1))) unsigned int*)g,
                                   (__attribute__((address_space(3))) unsigned int*)l, 16, 0, 0);
}
__device__ __forceinline__ void gl_lds4(const void* g, void* l) {
  __builtin_amdgcn_global_load_lds((const __attribute__((address_space(1))) unsigned int*)g,
                                   (__attribute__((address_space(3))) unsigned int*)l, 4, 0, 0);
}

// ---------------- weight convert / transpose ----------------
struct ConvJob { const float* src; unsigned short* dst; int rows, cols, trans; };
struct ConvJobs { ConvJob j[12]; };

__global__ void k_conv(ConvJobs jobs) {
  ConvJob jb = jobs.j[blockIdx.z];
  int n = jb.rows * jb.cols;
  for (int i = blockIdx.x * blockDim.x + threadIdx.x; i < n; i += gridDim.x * blockDim.x) {
    float v;
    if (jb.trans) {
      int col = i / jb.rows;            // out (cols, rows): out[col][row] = in[row][col]
      int row = i - col * jb.rows;
      v = jb.src[(size_t)row * jb.cols + col];
    } else {
      v = jb.src[i];
    }
    jb.dst[i] = f2bu(v);
  }
}

__global__ void k_zero(unsigned int* p) { if (threadIdx.x < 8) p[threadIdx.x] = 0u; }

// ---------------- token shift prologue ----------------
__global__ void k_prologue(const float* __restrict__ x,
    const float* __restrict__ mr, const float* __restrict__ mw, const float* __restrict__ mk,
    const float* __restrict__ mv, const float* __restrict__ ma, const float* __restrict__ mg,
    unsigned short* __restrict__ xr, unsigned short* __restrict__ xw, unsigned short* __restrict__ xk,
    unsigned short* __restrict__ xv, unsigned short* __restrict__ xa, unsigned short* __restrict__ xg)
{
  int i = blockIdx.x * 256 + threadIdx.x;
  if (i >= ELq) return;
  float xc = x[i];
  int t = (i >> 11) & (Tq - 1);
  float xp = t ? x[i - Cq] : 0.f;
  float dx = xp - xc;
  int c = i & (Cq - 1);
  xr[i] = f2bu(xc + dx * mr[c]);
  xw[i] = f2bu(xc + dx * mw[c]);
  xk[i] = f2bu(xc + dx * mk[c]);
  xv[i] = f2bu(xc + dx * mv[c]);
  xa[i] = f2bu(xc + dx * ma[c]);
  xg[i] = f2bu(xc + dx * mg[c]);
}

// ---------------- GEMM (A MxK row-major bf16, B NxK row-major bf16; C = A*B^T) ----------------
struct GJob {
  const unsigned short* A; const unsigned short* B;
  const float* bias; float* Cf; unsigned short* Cb;
  unsigned int* amax; const unsigned int* flag;
  int K; int epi;
};
struct GJobs { GJob j[4]; };

// epi: 0 f32 | 1 f32+bias | 2 f32 sigmoid(v+bias) | 3 bf16 tanh | 4 bf16 | 5 bf16 sigmoid
//      6 bf16+absmax | 7 f32+absmax | 8 f32*flagscale
__device__ __forceinline__ void epi_store(int epi, float v, size_t o,
    float* Cf, unsigned short* Cb, const float* bias, int col, float scale, float& lmax)
{
  switch (epi) {
    case 0: Cf[o] = v; break;
    case 1: Cf[o] = v + bias[col]; break;
    case 2: Cf[o] = 1.f / (1.f + expf(-(v + bias[col]))); break;
    case 3: Cb[o] = f2bu(tanhf(v)); break;
    case 4: Cb[o] = f2bu(v); break;
    case 5: Cb[o] = f2bu(1.f / (1.f + expf(-v))); break;
    case 6: lmax = fmaxf(lmax, fabsf(v)); Cb[o] = f2bu(v); break;
    case 7: lmax = fmaxf(lmax, fabsf(v)); Cf[o] = v; break;
    case 8: Cf[o] = v * scale; break;
  }
}

__global__ __launch_bounds__(256, 2) void k_gemm128(GJobs jobs) {
  GJob jb = jobs.j[blockIdx.z];
  __shared__ __align__(16) unsigned short As[128 * 32];
  __shared__ __align__(16) unsigned short Bs[128 * 32];
  __shared__ float sred[4];
  const int tid = threadIdx.x, lane = tid & 63, wid = tid >> 6;
  const int wr = wid >> 1, wc = wid & 1;
  const int m0 = blockIdx.y * 128, n0 = blockIdx.x * 128;
  const int K = jb.K;
  const unsigned short* A = jb.A; const unsigned short* B = jb.B;
  f32x4 acc[4][4] = {};
  for (int k0 = 0; k0 < K; k0 += 32) {
    #pragma unroll
    for (int i = 0; i < 2; ++i) {
      int cw = wid * 64 + i * 256;   // wave-uniform chunk base
      int c = cw + lane;
      int row = c >> 2, q = c & 3;
      gl_lds16(A + (size_t)(m0 + row) * K + k0 + q * 8, &As[cw * 8]);
      gl_lds16(B + (size_t)(n0 + row) * K + k0 + q * 8, &Bs[cw * 8]);
    }
    __syncthreads();
    const int kg = (lane >> 4) * 8;
    bf16x8 af[4], bq[4];
    #pragma unroll
    for (int mi = 0; mi < 4; ++mi)
      af[mi] = *(const bf16x8*)&As[(wr * 64 + mi * 16 + (lane & 15)) * 32 + kg];
    #pragma unroll
    for (int ni = 0; ni < 4; ++ni)
      bq[ni] = *(const bf16x8*)&Bs[(wc * 64 + ni * 16 + (lane & 15)) * 32 + kg];
    #pragma unroll
    for (int mi = 0; mi < 4; ++mi)
      #pragma unroll
      for (int ni = 0; ni < 4; ++ni)
        acc[mi][ni] = __builtin_amdgcn_mfma_f32_16x16x32_bf16(af[mi], bq[ni], acc[mi][ni], 0, 0, 0);
    __syncthreads();
  }
  float scale = 1.f;
  if (jb.epi == 8) scale = (__uint_as_float(*jb.flag) > 179.2f) ? 0.5f : 1.f;
  float lmax = 0.f;
  #pragma unroll
  for (int mi = 0; mi < 4; ++mi)
    #pragma unroll
    for (int ni = 0; ni < 4; ++ni) {
      int col = n0 + wc * 64 + ni * 16 + (lane & 15);
      int row = m0 + wr * 64 + mi * 16 + ((lane >> 4) << 2);
      #pragma unroll
      for (int q = 0; q < 4; ++q)
        epi_store(jb.epi, acc[mi][ni][q], (size_t)(row + q) * 2048 + col,
                  jb.Cf, jb.Cb, jb.bias, col, scale, lmax);
    }
  if (jb.epi == 6 || jb.epi == 7) {
    #pragma unroll
    for (int o = 32; o; o >>= 1) lmax = fmaxf(lmax, __shfl_xor(lmax, o));
    if (lane == 0) sred[wid] = lmax;
    __syncthreads();
    if (tid == 0)
      atomicMax(jb.amax, __float_as_uint(fmaxf(fmaxf(sred[0], sred[1]), fmaxf(sred[2], sred[3]))));
  }
}

template<int TBN>
__global__ __launch_bounds__(256, 2) void k_gemmN(GJob jb) {
  __shared__ __align__(16) unsigned short As[128 * 32];
  __shared__ __align__(16) unsigned short Bs[TBN * 32];
  __shared__ float sred[4];
  const int tid = threadIdx.x, lane = tid & 63, wid = tid >> 6;
  const int m0 = blockIdx.x * 128;
  const int K = jb.K;
  constexpr int NF = TBN / 16;
  const unsigned short* A = jb.A; const unsigned short* B = jb.B;
  f32x4 acc[2][NF] = {};
  for (int k0 = 0; k0 < K; k0 += 32) {
    for (int cw = wid * 64; cw < 512; cw += 256) {
      int c = cw + lane; int row = c >> 2, q = c & 3;
      gl_lds16(A + (size_t)(m0 + row) * K + k0 + q * 8, &As[cw * 8]);
    }
    for (int cw = wid * 64; cw < TBN * 4; cw += 256) {
      int c = cw + lane; int row = c >> 2, q = c & 3;
      gl_lds16(B + (size_t)row * K + k0 + q * 8, &Bs[cw * 8]);
    }
    __syncthreads();
    const int kg = (lane >> 4) * 8;
    bf16x8 af[2], bq[NF];
    #pragma unroll
    for (int mi = 0; mi < 2; ++mi)
      af[mi] = *(const bf16x8*)&As[(wid * 32 + mi * 16 + (lane & 15)) * 32 + kg];
    #pragma unroll
    for (int ni = 0; ni < NF; ++ni)
      bq[ni] = *(const bf16x8*)&Bs[(ni * 16 + (lane & 15)) * 32 + kg];
    #pragma unroll
    for (int mi = 0; mi < 2; ++mi)
      #pragma unroll
      for (int ni = 0; ni < NF; ++ni)
        acc[mi][ni] = __builtin_amdgcn_mfma_f32_16x16x32_bf16(af[mi], bq[ni], acc[mi][ni], 0, 0, 0);
    __syncthreads();
  }
  float lmax = 0.f;
  #pragma unroll
  for (int mi = 0; mi < 2; ++mi)
    #pragma unroll
    for (int ni = 0; ni < NF; ++ni) {
      int col = ni * 16 + (lane & 15);
      int row = m0 + wid * 32 + mi * 16 + ((lane >> 4) << 2);
      #pragma unroll
      for (int q = 0; q < 4; ++q)
        epi_store(jb.epi, acc[mi][ni][q], (size_t)(row + q) * TBN + col,
                  jb.Cf, jb.Cb, jb.bias, col, 1.f, lmax);
    }
  if (jb.epi == 6 || jb.epi == 7) {
    #pragma unroll
    for (int o = 32; o; o >>= 1) lmax = fmaxf(lmax, __shfl_xor(lmax, o));
    if (lane == 0) sred[wid] = lmax;
    __syncthreads();
    if (tid == 0)
      atomicMax(jb.amax, __float_as_uint(fmaxf(fmaxf(sred[0], sred[1]), fmaxf(sred[2], sred[3]))));
  }
}

// ---------------- absmax(v_first - v_raw) ----------------
__global__ void k_absmax_diff(const float* __restrict__ a, const float* __restrict__ b, unsigned int* out) {
  float m = 0.f;
  for (int i = blockIdx.x * blockDim.x + threadIdx.x; i < ELq; i += gridDim.x * blockDim.x)
    m = fmaxf(m, fabsf(a[i] - b[i]));
  #pragma unroll
  for (int o = 32; o; o >>= 1) m = fmaxf(m, __shfl_xor(m, o));
  __shared__ float sred[4];
  int lane = threadIdx.x & 63, wid = threadIdx.x >> 6;
  if (lane == 0) sred[wid] = m;
  __syncthreads();
  if (threadIdx.x == 0)
    atomicMax(out, __float_as_uint(fmaxf(fmaxf(sred[0], sred[1]), fmaxf(sred[2], sred[3]))));
}

// ---------------- v residual gating (in place over v_raw) ----------------
__global__ void k_vfin(float* __restrict__ v, const float* __restrict__ vf, const float* __restrict__ z,
                       const float* __restrict__ v0, const unsigned int* __restrict__ sc) {
  int i = blockIdx.x * 256 + threadIdx.x;
  if (i >= ELq) return;
  float m1 = fmaxf(__uint_as_float(sc[0]), 1.f);
  float m2 = fmaxf(__uint_as_float(sc[1]) / m1, 1.f);
  float mvd = fmaxf(__uint_as_float(sc[2]), 1.f);
  int c = i & (Cq - 1);
  float gx = v0[c] + z[i] / (m1 * m2);
  gx = fminf(fmaxf(gx, -16.f), 16.f);
  float gate = 1.f / (1.f + expf(-gx));
  float vr = v[i];
  v[i] = vr + (vf[i] - vr) * (gate / mvd);
}

// ---------------- wkv stream prep: kk-norm, k-final, decay, a/b streams ----------------
__global__ __launch_bounds__(256) void k_prep(float* __restrict__ k, float* __restrict__ w,
    float* __restrict__ asig, float* __restrict__ kkout,
    const float* __restrict__ kkw, const float* __restrict__ kaw) {
  int wid = threadIdx.x >> 6, lane = threadIdx.x & 63;
  int idx = blockIdx.x * 4 + wid;          // (b*T + t)*H + h
  size_t off = (size_t)idx * 64 + lane;
  int c = ((idx & (Hq - 1)) << 6) | lane;  // h*64 + n
  float kr = k[off];
  float kkv = kr * kkw[c];
  float ss = kkv * kkv;
  #pragma unroll
  for (int o = 32; o; o >>= 1) ss += __shfl_xor(ss, o);
  float kkn = kkv / fmaxf(sqrtf(ss), 1e-12f);
  float as = asig[off];
  kkout[off] = -kkn;                       // a-stream
  asig[off] = kkn * as;                    // b-stream (overwrite after read)
  k[off] = kr * (1.f + (as - 1.f) * kaw[c]);
  float wl = w[off];
  float wlog = -log1pf(expf(-wl)) - 0.5f;  // -softplus(-wlog) - 0.5
  w[off] = expf(-expf(wlog));              // decay in (0,1)
}

// ---------------- wkv7 scan: row-parallel, 1 wave per (b,h,row-quarter) ----------------
// Rows i of S are independent: S_i <- S_i*w + (S_i.a)*b + v_i*k ; y_i = S_i.r
// Block = 16 rows of one head. lane: row = rq*16 + (lane>>2), cols [ (lane&3)*16, +16 ).
// sa / y reductions: 2x shfl_xor across the 4 lanes of a row. Zero barriers.
// Streams staged via global_load_lds, 8-slot ring, depth-4 prefetch, counted vmcnt.
__global__ __launch_bounds__(64) void k_wkv(
    const float* __restrict__ rS, const float* __restrict__ wS, const float* __restrict__ kS,
    const float* __restrict__ vS, const float* __restrict__ aS, const float* __restrict__ bS,
    float* __restrict__ y, unsigned int* __restrict__ ymax) {
  const int lane = threadIdx.x;
  const int bh = blockIdx.x >> 2;          // b*32 + h
  const int rq = blockIdx.x & 3;           // row quarter
  const int row = rq * 16 + (lane >> 2);
  const int cq = lane & 3;
  __shared__ __align__(16) float Ls[8][6][64];   // ring: r,w,k,a,b,v(16 used)
  float S[16];
  #pragma unroll
  for (int q = 0; q < 16; ++q) S[q] = 0.f;
  const size_t base0 = (size_t)(bh >> 5) * Tq * Cq + (size_t)(bh & 31) * 64;

  auto stage = [&](int t, int slot) {
    size_t sb = base0 + (size_t)t * Cq;
    gl_lds4(rS + sb + lane, &Ls[slot][0][0]);
    gl_lds4(wS + sb + lane, &Ls[slot][1][0]);
    gl_lds4(kS + sb + lane, &Ls[slot][2][0]);
    gl_lds4(aS + sb + lane, &Ls[slot][3][0]);
    gl_lds4(bS + sb + lane, &Ls[slot][4][0]);
    gl_lds4(vS + sb + rq * 16 + (lane & 15), &Ls[slot][5][0]);
  };
  stage(0, 0); stage(1, 1); stage(2, 2); stage(3, 3);

  float ymx = 0.f;
  for (int t = 0; t < Tq; ++t) {
    const int sl = t & 7;
    // newest 18 vmem ops were all issued after stage(t) -> stage(t) complete
    asm volatile("s_waitcnt vmcnt(18)" ::: "memory");
    __builtin_amdgcn_sched_barrier(0);
    const float4* Ap = (const float4*)&Ls[sl][3][cq * 16];
    float4 a0 = Ap[0], a1 = Ap[1], a2 = Ap[2], a3 = Ap[3];
    float vi = Ls[sl][5][lane >> 2];
    float sa = (S[0]*a0.x + S[1]*a0.y + S[2]*a0.z + S[3]*a0.w)
             + (S[4]*a1.x + S[5]*a1.y + S[6]*a1.z + S[7]*a1.w)
             + (S[8]*a2.x + S[9]*a2.y + S[10]*a2.z + S[11]*a2.w)
             + (S[12]*a3.x + S[13]*a3.y + S[14]*a3.z + S[15]*a3.w);
    sa += __shfl_xor(sa, 1);
    sa += __shfl_xor(sa, 2);
    const float4* Rp = (const float4*)&Ls[sl][0][cq * 16];
    const float4* Wp = (const float4*)&Ls[sl][1][cq * 16];
    const float4* Kp = (const float4*)&Ls[sl][2][cq * 16];
    const float4* Bp = (const float4*)&Ls[sl][4][cq * 16];
    float yp = 0.f;
    #pragma unroll
    for (int g = 0; g < 4; ++g) {
      float4 w4 = Wp[g], k4 = Kp[g], b4 = Bp[g], r4 = Rp[g];
      float s0 = S[4*g+0] * w4.x + (sa * b4.x + vi * k4.x);
      float s1 = S[4*g+1] * w4.y + (sa * b4.y + vi * k4.y);
      float s2 = S[4*g+2] * w4.z + (sa * b4.z + vi * k4.z);
      float s3 = S[4*g+3] * w4.w + (sa * b4.w + vi * k4.w);
      S[4*g+0] = s0; S[4*g+1] = s1; S[4*g+2] = s2; S[4*g+3] = s3;
      yp += s0 * r4.x; yp += s1 * r4.y; yp += s2 * r4.z; yp += s3 * r4.w;
    }
    yp += __shfl_xor(yp, 1);
    yp += __shfl_xor(yp, 2);
    if (cq == 0) {
      y[base0 + (size_t)t * Cq + row] = yp;
      ymx = fmaxf(ymx, fabsf(yp));
    }
    int tn = (t + 4 < Tq) ? t + 4 : Tq - 1;
    stage(tn, (t + 4) & 7);
  }
  #pragma unroll
  for (int o = 32; o; o >>= 1) ymx = fmaxf(ymx, __shfl_xor(ymx, o));
  if (lane == 0) atomicMax(ymax, __float_as_uint(ymx));
}

// ---------------- groupnorm + bonus + gate ----------------
__global__ __launch_bounds__(256) void k_epi1(const float* __restrict__ y, const float* __restrict__ r,
    const float* __restrict__ k, const float* __restrict__ v, const unsigned short* __restrict__ g,
    const float* __restrict__ lnw, const float* __restrict__ lnb, const float* __restrict__ rk,
    unsigned short* __restrict__ yg) {
  int wid = threadIdx.x >> 6, lane = threadIdx.x & 63;
  int idx = blockIdx.x * 4 + wid;
  size_t off = (size_t)idx * 64 + lane;
  int c = ((idx & (Hq - 1)) << 6) | lane;
  float yv = y[off];
  float s = yv;
  #pragma unroll
  for (int o = 32; o; o >>= 1) s += __shfl_xor(s, o);
  float mu = s * (1.f / 64.f);
  float d = yv - mu;
  float vs = d * d;
  #pragma unroll
  for (int o = 32; o; o >>= 1) vs += __shfl_xor(vs, o);
  float yn = d / sqrtf(vs * (1.f / 64.f) + 6.4e-4f);
  float yo = yn * lnw[c] + lnb[c];
  float bon = r[off] * k[off] * rk[c];
  #pragma unroll
  for (int o = 32; o; o >>= 1) bon += __shfl_xor(bon, o);
  yo += bon * v[off];
  yg[off] = f2bu(yo * b2f(g[off]));
}

// ---------------- v_first output ----------------
__global__ void k_vout(const float* __restrict__ vf, const unsigned int* __restrict__ sc,
                       float* __restrict__ out) {
  int i = blockIdx.x * 256 + threadIdx.x;
  if (i >= ELq) return;
  float s = (__uint_as_float(sc[3]) > 179.2f) ? 0.5f : 1.f;
  out[i] = vf[i] * s;
}

extern "C" void kernel_launch(void* const* d_in, const int* in_sizes, int n_in,
                              void* d_out, int out_size, void* d_ws, size_t ws_size,
                              hipStream_t stream) {
  const float* x      = (const float*)d_in[0];
  const float* vfirst = (const float*)d_in[1];
  const float* x_r = (const float*)d_in[2];
  const float* x_w = (const float*)d_in[3];
  const float* x_k = (const float*)d_in[4];
  const float* x_v = (const float*)d_in[5];
  const float* x_a = (const float*)d_in[6];
  const float* x_g = (const float*)d_in[7];
  const float* w0 = (const float*)d_in[8];
  const float* w1 = (const float*)d_in[9];
  const float* w2 = (const float*)d_in[10];
  const float* a0 = (const float*)d_in[11];
  const float* a1 = (const float*)d_in[12];
  const float* a2 = (const float*)d_in[13];
  const float* v0 = (const float*)d_in[14];
  const float* v1 = (const float*)d_in[15];
  const float* v2 = (const float*)d_in[16];
  const float* g1 = (const float*)d_in[17];
  const float* g2 = (const float*)d_in[18];
  const float* k_k = (const float*)d_in[19];
  const float* k_a = (const float*)d_in[20];
  const float* r_k = (const float*)d_in[21];
  const float* W_r = (const float*)d_in[22];
  const float* W_k = (const float*)d_in[23];
  const float* W_v = (const float*)d_in[24];
  const float* W_o = (const float*)d_in[25];
  const float* lnw = (const float*)d_in[26];
  const float* lnb = (const float*)d_in[27];

  char* ws = (char*)d_ws;
  size_t off = 0;
  auto alloc = [&](size_t bytes) -> void* {
    void* p = ws + off; off += (bytes + 255) & ~(size_t)255; return p;
  };
  unsigned int* scal = (unsigned int*)alloc(256);      // [M1, MZ, MVD, MY]
  float* kbuf  = (float*)alloc((size_t)ELq * 4);
  float* vbuf  = (float*)alloc((size_t)ELq * 4);
  float* wbuf  = (float*)alloc((size_t)ELq * 4);
  float* abuf  = (float*)alloc((size_t)ELq * 4);
  float* kkbuf = (float*)alloc((size_t)ELq * 4);
  float* ybuf  = (float*)alloc((size_t)ELq * 4);
  unsigned short* xrb = (unsigned short*)alloc((size_t)ELq * 2);
  unsigned short* xwb = (unsigned short*)alloc((size_t)ELq * 2);
  unsigned short* xkb = (unsigned short*)alloc((size_t)ELq * 2);
  unsigned short* xvb = (unsigned short*)alloc((size_t)ELq * 2);
  unsigned short* xab = (unsigned short*)alloc((size_t)ELq * 2);
  unsigned short* xgb = (unsigned short*)alloc((size_t)ELq * 2);
  unsigned short* gbuf = (unsigned short*)alloc((size_t)ELq * 2);
  unsigned short* ygb  = (unsigned short*)alloc((size_t)ELq * 2);
  unsigned short* WrB = (unsigned short*)alloc((size_t)ELq * 2);
  unsigned short* WkB = (unsigned short*)alloc((size_t)ELq * 2);
  unsigned short* WvB = (unsigned short*)alloc((size_t)ELq * 2);
  unsigned short* WoB = (unsigned short*)alloc((size_t)ELq * 2);
  unsigned short* w1T = (unsigned short*)alloc(64 * 2048 * 2);
  unsigned short* a1T = (unsigned short*)alloc(64 * 2048 * 2);
  unsigned short* v1T = (unsigned short*)alloc(32 * 2048 * 2);
  unsigned short* g1T = (unsigned short*)alloc(128 * 2048 * 2);
  unsigned short* w2T = (unsigned short*)alloc(2048 * 64 * 2);
  unsigned short* a2T = (unsigned short*)alloc(2048 * 64 * 2);
  unsigned short* v2T = (unsigned short*)alloc(2048 * 32 * 2);
  unsigned short* g2T = (unsigned short*)alloc(2048 * 128 * 2);
  unsigned short* hwb = (unsigned short*)alloc((size_t)Mq * 64 * 2);
  unsigned short* hab = (unsigned short*)alloc((size_t)Mq * 64 * 2);
  unsigned short* hvb = (unsigned short*)alloc((size_t)Mq * 32 * 2);
  unsigned short* hgb = (unsigned short*)alloc((size_t)Mq * 128 * 2);
  // d_out doubles as scratch: r in first half (dead before final GEMM writes y there),
  // z in second half (dead before k_vout writes v_first_out there).
  float* rbuf = (float*)d_out;
  float* zbuf = (float*)d_out + ELq;
  float* yout = (float*)d_out;
  float* vfout = (float*)d_out + ELq;

  k_zero<<<1, 64, 0, stream>>>(scal);

  ConvJobs cj;
  cj.j[0]  = {W_r, WrB, Cq, Cq, 0};
  cj.j[1]  = {W_k, WkB, Cq, Cq, 0};
  cj.j[2]  = {W_v, WvB, Cq, Cq, 0};
  cj.j[3]  = {W_o, WoB, Cq, Cq, 0};
  cj.j[4]  = {w1, w1T, 2048, 64, 1};
  cj.j[5]  = {a1, a1T, 2048, 64, 1};
  cj.j[6]  = {v1, v1T, 2048, 32, 1};
  cj.j[7]  = {g1, g1T, 2048, 128, 1};
  cj.j[8]  = {w2, w2T, 64, 2048, 1};
  cj.j[9]  = {a2, a2T, 64, 2048, 1};
  cj.j[10] = {v2, v2T, 32, 2048, 1};
  cj.j[11] = {g2, g2T, 128, 2048, 1};
  k_conv<<<dim3(1024, 1, 12), 256, 0, stream>>>(cj);

  k_prologue<<<ELq / 256, 256, 0, stream>>>(x, x_r, x_w, x_k, x_v, x_a, x_g,
                                            xrb, xwb, xkb, xvb, xab, xgb);

  GJobs g1j;
  g1j.j[0] = {xrb, WrB, nullptr, rbuf, nullptr, nullptr, nullptr, 2048, 0};
  g1j.j[1] = {xkb, WkB, nullptr, kbuf, nullptr, nullptr, nullptr, 2048, 0};
  g1j.j[2] = {xvb, WvB, nullptr, vbuf, nullptr, nullptr, nullptr, 2048, 0};
  g1j.j[3] = g1j.j[0];
  k_gemm128<<<dim3(16, 16, 3), 256, 0, stream>>>(g1j);

  GJob jw = {xwb, w1T, nullptr, nullptr, hwb, nullptr, nullptr, 2048, 3};
  k_gemmN<64><<<16, 256, 0, stream>>>(jw);
  GJob ja = {xab, a1T, nullptr, nullptr, hab, nullptr, nullptr, 2048, 4};
  k_gemmN<64><<<16, 256, 0, stream>>>(ja);
  GJob jv = {xvb, v1T, nullptr, nullptr, hvb, scal + 0, nullptr, 2048, 6};
  k_gemmN<32><<<16, 256, 0, stream>>>(jv);
  GJob jg = {xgb, g1T, nullptr, nullptr, hgb, nullptr, nullptr, 2048, 5};
  k_gemmN<128><<<16, 256, 0, stream>>>(jg);

  GJobs g3j;
  g3j.j[0] = {hwb, w2T, w0, wbuf, nullptr, nullptr, nullptr, 64, 1};
  g3j.j[1] = {hab, a2T, a0, abuf, nullptr, nullptr, nullptr, 64, 2};
  g3j.j[2] = {hvb, v2T, nullptr, zbuf, nullptr, scal + 1, nullptr, 32, 7};
  g3j.j[3] = {hgb, g2T, nullptr, nullptr, gbuf, nullptr, nullptr, 128, 4};
  k_gemm128<<<dim3(16, 16, 4), 256, 0, stream>>>(g3j);

  k_absmax_diff<<<1024, 256, 0, stream>>>(vfirst, vbuf, scal + 2);
  k_vfin<<<ELq / 256, 256, 0, stream>>>(vbuf, vfirst, zbuf, v0, scal);
  k_prep<<<(2 * Tq * Hq) / 4, 256, 0, stream>>>(kbuf, wbuf, abuf, kkbuf, k_k, k_a);
  k_wkv<<<4 * 2 * Hq, 64, 0, stream>>>(rbuf, wbuf, kbuf, vbuf, kkbuf, abuf, ybuf, scal + 3);
  k_epi1<<<(2 * Tq * Hq) / 4, 256, 0, stream>>>(ybuf, rbuf, kbuf, vbuf, gbuf, lnw, lnb, r_k, ygb);

  GJobs gfj;
  gfj.j[0] = {ygb, WoB, nullptr, yout, nullptr, nullptr, scal + 3, 2048, 8};
  gfj.j[1] = gfj.j[0]; gfj.j[2] = gfj.j[0]; gfj.j[3] = gfj.j[0];
  k_gemm128<<<dim3(16, 16, 1), 256, 0, stream>>>(gfj);

  k_vout<<<ELq / 256, 256, 0, stream>>>(vfirst, scal, vfout);
}

// Round 3
// 1010.450 us; speedup vs baseline: 1.4067x; 1.2418x over previous
//
#include <hip/hip_runtime.h>
#include <hip/hip_bf16.h>

#define ELq 4194304   // B*T*C
#define Cq 2048
#define Tq 1024
#define Hq 32
#define Mq 2048       // B*T

typedef __attribute__((ext_vector_type(8))) short bf16x8;
typedef __attribute__((ext_vector_type(4))) float f32x4;

__device__ __forceinline__ unsigned short f2bu(float f) {
  union { float f; unsigned u; } v; v.f = f;
  unsigned r = v.u + 0x7fffu + ((v.u >> 16) & 1u);
  return (unsigned short)(r >> 16);
}
__device__ __forceinline__ float b2f(unsigned short u) {
  union { unsigned u; float f; } v; v.u = ((unsigned)u) << 16;
  return v.f;
}
__device__ __forceinline__ void gl_lds16(const void* g, void* l) {
  __builtin_amdgcn_global_load_lds((const __attribute__((address_space(1))) unsigned int*)g,
                                   (__attribute__((address_space(3))) unsigned int*)l, 16, 0, 0);
}
__device__ __forceinline__ void gl_lds4(const void* g, void* l) {
  __builtin_amdgcn_global_load_lds((const __attribute__((address_space(1))) unsigned int*)g,
                                   (__attribute__((address_space(3))) unsigned int*)l, 4, 0, 0);
}

// DPP cross-lane add: x + lane-permuted x. VALU-pipe (no LDS), ~4-8 cyc.
template<int CTRL>
__device__ __forceinline__ float dpp_add(float x) {
  int t = __builtin_amdgcn_update_dpp(0, __builtin_bit_cast(int, x), CTRL, 0xF, 0xF, true);
  return x + __builtin_bit_cast(float, t);
}

// ---------------- weight convert / transpose ----------------
struct ConvJob { const float* src; unsigned short* dst; int rows, cols, trans; };
struct ConvJobs { ConvJob j[12]; };

__global__ void k_conv(ConvJobs jobs) {
  ConvJob jb = jobs.j[blockIdx.z];
  int n = jb.rows * jb.cols;
  for (int i = blockIdx.x * blockDim.x + threadIdx.x; i < n; i += gridDim.x * blockDim.x) {
    float v;
    if (jb.trans) {
      int col = i / jb.rows;            // out (cols, rows): out[col][row] = in[row][col]
      int row = i - col * jb.rows;
      v = jb.src[(size_t)row * jb.cols + col];
    } else {
      v = jb.src[i];
    }
    jb.dst[i] = f2bu(v);
  }
}

__global__ void k_zero(unsigned int* p) { if (threadIdx.x < 8) p[threadIdx.x] = 0u; }

// ---------------- token shift prologue ----------------
__global__ void k_prologue(const float* __restrict__ x,
    const float* __restrict__ mr, const float* __restrict__ mw, const float* __restrict__ mk,
    const float* __restrict__ mv, const float* __restrict__ ma, const float* __restrict__ mg,
    unsigned short* __restrict__ xr, unsigned short* __restrict__ xw, unsigned short* __restrict__ xk,
    unsigned short* __restrict__ xv, unsigned short* __restrict__ xa, unsigned short* __restrict__ xg)
{
  int i = blockIdx.x * 256 + threadIdx.x;
  if (i >= ELq) return;
  float xc = x[i];
  int t = (i >> 11) & (Tq - 1);
  float xp = t ? x[i - Cq] : 0.f;
  float dx = xp - xc;
  int c = i & (Cq - 1);
  xr[i] = f2bu(xc + dx * mr[c]);
  xw[i] = f2bu(xc + dx * mw[c]);
  xk[i] = f2bu(xc + dx * mk[c]);
  xv[i] = f2bu(xc + dx * mv[c]);
  xa[i] = f2bu(xc + dx * ma[c]);
  xg[i] = f2bu(xc + dx * mg[c]);
}

// ---------------- GEMM (A MxK row-major bf16, B NxK row-major bf16; C = A*B^T) ----------------
struct GJob {
  const unsigned short* A; const unsigned short* B;
  const float* bias; float* Cf; unsigned short* Cb;
  unsigned int* amax; const unsigned int* flag;
  int K; int epi;
};
struct GJobs { GJob j[4]; };

// epi: 0 f32 | 1 f32+bias | 2 f32 sigmoid(v+bias) | 3 bf16 tanh | 4 bf16 | 5 bf16 sigmoid
//      6 bf16+absmax | 7 f32+absmax | 8 f32*flagscale
__device__ __forceinline__ void epi_store(int epi, float v, size_t o,
    float* Cf, unsigned short* Cb, const float* bias, int col, float scale, float& lmax)
{
  switch (epi) {
    case 0: Cf[o] = v; break;
    case 1: Cf[o] = v + bias[col]; break;
    case 2: Cf[o] = 1.f / (1.f + expf(-(v + bias[col]))); break;
    case 3: Cb[o] = f2bu(tanhf(v)); break;
    case 4: Cb[o] = f2bu(v); break;
    case 5: Cb[o] = f2bu(1.f / (1.f + expf(-v))); break;
    case 6: lmax = fmaxf(lmax, fabsf(v)); Cb[o] = f2bu(v); break;
    case 7: lmax = fmaxf(lmax, fabsf(v)); Cf[o] = v; break;
    case 8: Cf[o] = v * scale; break;
  }
}

__global__ __launch_bounds__(256, 2) void k_gemm128(GJobs jobs) {
  GJob jb = jobs.j[blockIdx.z];
  __shared__ __align__(16) unsigned short As[128 * 32];
  __shared__ __align__(16) unsigned short Bs[128 * 32];
  __shared__ float sred[4];
  const int tid = threadIdx.x, lane = tid & 63, wid = tid >> 6;
  const int wr = wid >> 1, wc = wid & 1;
  const int m0 = blockIdx.y * 128, n0 = blockIdx.x * 128;
  const int K = jb.K;
  const unsigned short* A = jb.A; const unsigned short* B = jb.B;
  f32x4 acc[4][4] = {};
  for (int k0 = 0; k0 < K; k0 += 32) {
    #pragma unroll
    for (int i = 0; i < 2; ++i) {
      int cw = wid * 64 + i * 256;   // wave-uniform chunk base
      int c = cw + lane;
      int row = c >> 2, q = c & 3;
      gl_lds16(A + (size_t)(m0 + row) * K + k0 + q * 8, &As[cw * 8]);
      gl_lds16(B + (size_t)(n0 + row) * K + k0 + q * 8, &Bs[cw * 8]);
    }
    __syncthreads();
    const int kg = (lane >> 4) * 8;
    bf16x8 af[4], bq[4];
    #pragma unroll
    for (int mi = 0; mi < 4; ++mi)
      af[mi] = *(const bf16x8*)&As[(wr * 64 + mi * 16 + (lane & 15)) * 32 + kg];
    #pragma unroll
    for (int ni = 0; ni < 4; ++ni)
      bq[ni] = *(const bf16x8*)&Bs[(wc * 64 + ni * 16 + (lane & 15)) * 32 + kg];
    #pragma unroll
    for (int mi = 0; mi < 4; ++mi)
      #pragma unroll
      for (int ni = 0; ni < 4; ++ni)
        acc[mi][ni] = __builtin_amdgcn_mfma_f32_16x16x32_bf16(af[mi], bq[ni], acc[mi][ni], 0, 0, 0);
    __syncthreads();
  }
  float scale = 1.f;
  if (jb.epi == 8) scale = (__uint_as_float(*jb.flag) > 179.2f) ? 0.5f : 1.f;
  float lmax = 0.f;
  #pragma unroll
  for (int mi = 0; mi < 4; ++mi)
    #pragma unroll
    for (int ni = 0; ni < 4; ++ni) {
      int col = n0 + wc * 64 + ni * 16 + (lane & 15);
      int row = m0 + wr * 64 + mi * 16 + ((lane >> 4) << 2);
      #pragma unroll
      for (int q = 0; q < 4; ++q)
        epi_store(jb.epi, acc[mi][ni][q], (size_t)(row + q) * 2048 + col,
                  jb.Cf, jb.Cb, jb.bias, col, scale, lmax);
    }
  if (jb.epi == 6 || jb.epi == 7) {
    #pragma unroll
    for (int o = 32; o; o >>= 1) lmax = fmaxf(lmax, __shfl_xor(lmax, o));
    if (lane == 0) sred[wid] = lmax;
    __syncthreads();
    if (tid == 0)
      atomicMax(jb.amax, __float_as_uint(fmaxf(fmaxf(sred[0], sred[1]), fmaxf(sred[2], sred[3]))));
  }
}

template<int TBN>
__global__ __launch_bounds__(256, 2) void k_gemmN(GJob jb) {
  __shared__ __align__(16) unsigned short As[128 * 32];
  __shared__ __align__(16) unsigned short Bs[TBN * 32];
  __shared__ float sred[4];
  const int tid = threadIdx.x, lane = tid & 63, wid = tid >> 6;
  const int m0 = blockIdx.x * 128;
  const int K = jb.K;
  constexpr int NF = TBN / 16;
  const unsigned short* A = jb.A; const unsigned short* B = jb.B;
  f32x4 acc[2][NF] = {};
  for (int k0 = 0; k0 < K; k0 += 32) {
    for (int cw = wid * 64; cw < 512; cw += 256) {
      int c = cw + lane; int row = c >> 2, q = c & 3;
      gl_lds16(A + (size_t)(m0 + row) * K + k0 + q * 8, &As[cw * 8]);
    }
    for (int cw = wid * 64; cw < TBN * 4; cw += 256) {
      int c = cw + lane; int row = c >> 2, q = c & 3;
      gl_lds16(B + (size_t)row * K + k0 + q * 8, &Bs[cw * 8]);
    }
    __syncthreads();
    const int kg = (lane >> 4) * 8;
    bf16x8 af[2], bq[NF];
    #pragma unroll
    for (int mi = 0; mi < 2; ++mi)
      af[mi] = *(const bf16x8*)&As[(wid * 32 + mi * 16 + (lane & 15)) * 32 + kg];
    #pragma unroll
    for (int ni = 0; ni < NF; ++ni)
      bq[ni] = *(const bf16x8*)&Bs[(ni * 16 + (lane & 15)) * 32 + kg];
    #pragma unroll
    for (int mi = 0; mi < 2; ++mi)
      #pragma unroll
      for (int ni = 0; ni < NF; ++ni)
        acc[mi][ni] = __builtin_amdgcn_mfma_f32_16x16x32_bf16(af[mi], bq[ni], acc[mi][ni], 0, 0, 0);
    __syncthreads();
  }
  float lmax = 0.f;
  #pragma unroll
  for (int mi = 0; mi < 2; ++mi)
    #pragma unroll
    for (int ni = 0; ni < NF; ++ni) {
      int col = ni * 16 + (lane & 15);
      int row = m0 + wid * 32 + mi * 16 + ((lane >> 4) << 2);
      #pragma unroll
      for (int q = 0; q < 4; ++q)
        epi_store(jb.epi, acc[mi][ni][q], (size_t)(row + q) * TBN + col,
                  jb.Cf, jb.Cb, jb.bias, col, 1.f, lmax);
    }
  if (jb.epi == 6 || jb.epi == 7) {
    #pragma unroll
    for (int o = 32; o; o >>= 1) lmax = fmaxf(lmax, __shfl_xor(lmax, o));
    if (lane == 0) sred[wid] = lmax;
    __syncthreads();
    if (tid == 0)
      atomicMax(jb.amax, __float_as_uint(fmaxf(fmaxf(sred[0], sred[1]), fmaxf(sred[2], sred[3]))));
  }
}

// ---------------- absmax(v_first - v_raw) ----------------
__global__ void k_absmax_diff(const float* __restrict__ a, const float* __restrict__ b, unsigned int* out) {
  float m = 0.f;
  for (int i = blockIdx.x * blockDim.x + threadIdx.x; i < ELq; i += gridDim.x * blockDim.x)
    m = fmaxf(m, fabsf(a[i] - b[i]));
  #pragma unroll
  for (int o = 32; o; o >>= 1) m = fmaxf(m, __shfl_xor(m, o));
  __shared__ float sred[4];
  int lane = threadIdx.x & 63, wid = threadIdx.x >> 6;
  if (lane == 0) sred[wid] = m;
  __syncthreads();
  if (threadIdx.x == 0)
    atomicMax(out, __float_as_uint(fmaxf(fmaxf(sred[0], sred[1]), fmaxf(sred[2], sred[3]))));
}

// ---------------- v residual gating (in place over v_raw) ----------------
__global__ void k_vfin(float* __restrict__ v, const float* __restrict__ vf, const float* __restrict__ z,
                       const float* __restrict__ v0, const unsigned int* __restrict__ sc) {
  int i = blockIdx.x * 256 + threadIdx.x;
  if (i >= ELq) return;
  float m1 = fmaxf(__uint_as_float(sc[0]), 1.f);
  float m2 = fmaxf(__uint_as_float(sc[1]) / m1, 1.f);
  float mvd = fmaxf(__uint_as_float(sc[2]), 1.f);
  int c = i & (Cq - 1);
  float gx = v0[c] + z[i] / (m1 * m2);
  gx = fminf(fmaxf(gx, -16.f), 16.f);
  float gate = 1.f / (1.f + expf(-gx));
  float vr = v[i];
  v[i] = vr + (vf[i] - vr) * (gate / mvd);
}

// ---------------- wkv stream prep: kk-norm, k-final, decay, a/b streams ----------------
__global__ __launch_bounds__(256) void k_prep(float* __restrict__ k, float* __restrict__ w,
    float* __restrict__ asig, float* __restrict__ kkout,
    const float* __restrict__ kkw, const float* __restrict__ kaw) {
  int wid = threadIdx.x >> 6, lane = threadIdx.x & 63;
  int idx = blockIdx.x * 4 + wid;          // (b*T + t)*H + h
  size_t off = (size_t)idx * 64 + lane;
  int c = ((idx & (Hq - 1)) << 6) | lane;  // h*64 + n
  float kr = k[off];
  float kkv = kr * kkw[c];
  float ss = kkv * kkv;
  #pragma unroll
  for (int o = 32; o; o >>= 1) ss += __shfl_xor(ss, o);
  float kkn = kkv / fmaxf(sqrtf(ss), 1e-12f);
  float as = asig[off];
  kkout[off] = -kkn;                       // a-stream
  asig[off] = kkn * as;                    // b-stream (overwrite after read)
  k[off] = kr * (1.f + (as - 1.f) * kaw[c]);
  float wl = w[off];
  float wlog = -log1pf(expf(-wl)) - 0.5f;  // -softplus(-wlog) - 0.5
  w[off] = expf(-expf(wlog));              // decay in (0,1)
}

// ---------------- wkv7 scan: row-parallel, 8 lanes/row, DPP reductions ----------------
// Rows i of S are independent: S_i <- S_i*w + (S_i.a)*b + v_i*k ; y_i = S_i.r
// Block = 8 rows of one head (512 blocks). lane: row = rq*8 + (lane>>3),
// cols [(lane&7)*8, +8). Reductions: 3 DPP adds (xor1, xor2, half_mirror) — VALU pipe,
// zero LDS-pipe shuffles, zero barriers. Streams: gl_lds 8-slot ring, depth-4 prefetch,
// counted vmcnt(18); ds_reads software-pipelined one step ahead into registers.
struct SR { float4 r0, r1, w0, w1, k0, k1, a0, a1, b0, b1; float v; };

__device__ __forceinline__ void ld_sr(SR& R, const float (*L)[64], int cq8, int row) {
  R.r0 = *(const float4*)&L[0][cq8]; R.r1 = *(const float4*)&L[0][cq8 + 4];
  R.w0 = *(const float4*)&L[1][cq8]; R.w1 = *(const float4*)&L[1][cq8 + 4];
  R.k0 = *(const float4*)&L[2][cq8]; R.k1 = *(const float4*)&L[2][cq8 + 4];
  R.a0 = *(const float4*)&L[3][cq8]; R.a1 = *(const float4*)&L[3][cq8 + 4];
  R.b0 = *(const float4*)&L[4][cq8]; R.b1 = *(const float4*)&L[4][cq8 + 4];
  R.v  = L[5][row];
}

__device__ __forceinline__ void wkv_step(const SR& R, float S[8], float& ymx,
    float* __restrict__ y, size_t yoff, int lane) {
  float sa = (S[0]*R.a0.x + S[1]*R.a0.y) + (S[2]*R.a0.z + S[3]*R.a0.w)
           + (S[4]*R.a1.x + S[5]*R.a1.y) + (S[6]*R.a1.z + S[7]*R.a1.w);
  sa = dpp_add<0xB1>(sa);    // xor 1 (quad_perm [1,0,3,2])
  sa = dpp_add<0x4E>(sa);    // xor 2 (quad_perm [2,3,0,1])
  sa = dpp_add<0x141>(sa);   // row_half_mirror: other quad within 8
  float vi = R.v;
  float s0 = S[0]*R.w0.x + (sa*R.b0.x + vi*R.k0.x);
  float s1 = S[1]*R.w0.y + (sa*R.b0.y + vi*R.k0.y);
  float s2 = S[2]*R.w0.z + (sa*R.b0.z + vi*R.k0.z);
  float s3 = S[3]*R.w0.w + (sa*R.b0.w + vi*R.k0.w);
  float s4 = S[4]*R.w1.x + (sa*R.b1.x + vi*R.k1.x);
  float s5 = S[5]*R.w1.y + (sa*R.b1.y + vi*R.k1.y);
  float s6 = S[6]*R.w1.z + (sa*R.b1.z + vi*R.k1.z);
  float s7 = S[7]*R.w1.w + (sa*R.b1.w + vi*R.k1.w);
  S[0]=s0; S[1]=s1; S[2]=s2; S[3]=s3; S[4]=s4; S[5]=s5; S[6]=s6; S[7]=s7;
  float yp = (s0*R.r0.x + s1*R.r0.y) + (s2*R.r0.z + s3*R.r0.w)
           + (s4*R.r1.x + s5*R.r1.y) + (s6*R.r1.z + s7*R.r1.w);
  yp = dpp_add<0xB1>(yp);
  yp = dpp_add<0x4E>(yp);
  yp = dpp_add<0x141>(yp);
  if ((lane & 7) == 0) {
    y[yoff] = yp;
    ymx = fmaxf(ymx, fabsf(yp));
  }
}

__global__ __launch_bounds__(64, 1) void k_wkv(
    const float* __restrict__ rS, const float* __restrict__ wS, const float* __restrict__ kS,
    const float* __restrict__ vS, const float* __restrict__ aS, const float* __restrict__ bS,
    float* __restrict__ y, unsigned int* __restrict__ ymax) {
  const int lane = threadIdx.x;
  const int bh = blockIdx.x >> 3;          // b*32 + h
  const int rq = blockIdx.x & 7;           // row octet
  const int row = rq * 8 + (lane >> 3);
  const int cq8 = (lane & 7) * 8;
  __shared__ __align__(16) float Ls[8][6][64];   // ring: r,w,k,a,b,v
  float S[8];
  #pragma unroll
  for (int q = 0; q < 8; ++q) S[q] = 0.f;
  const size_t base0 = (size_t)(bh >> 5) * Tq * Cq + (size_t)(bh & 31) * 64;

  auto stage = [&](int t, int slot) {
    size_t sb = base0 + (size_t)t * Cq;
    gl_lds4(rS + sb + lane, &Ls[slot][0][0]);
    gl_lds4(wS + sb + lane, &Ls[slot][1][0]);
    gl_lds4(kS + sb + lane, &Ls[slot][2][0]);
    gl_lds4(aS + sb + lane, &Ls[slot][3][0]);
    gl_lds4(bS + sb + lane, &Ls[slot][4][0]);
    gl_lds4(vS + sb + lane, &Ls[slot][5][0]);
  };
  stage(0, 0); stage(1, 1); stage(2, 2); stage(3, 3);
  asm volatile("s_waitcnt vmcnt(18)" ::: "memory");   // stage(0) complete
  SR RA, RB;
  ld_sr(RA, Ls[0], cq8, row);

  float ymx = 0.f;
  for (int t = 0; t < Tq; t += 2) {
    int t4 = (t + 4 < Tq) ? t + 4 : Tq - 1;
    stage(t4, (t + 4) & 7);
    asm volatile("s_waitcnt vmcnt(18)" ::: "memory"); // stage(t+1) complete
    ld_sr(RB, Ls[(t + 1) & 7], cq8, row);
    wkv_step(RA, S, ymx, y, base0 + (size_t)t * Cq + row, lane);
    int t5 = (t + 5 < Tq) ? t + 5 : Tq - 1;
    stage(t5, (t + 5) & 7);
    asm volatile("s_waitcnt vmcnt(18)" ::: "memory"); // stage(t+2) complete
    ld_sr(RA, Ls[(t + 2) & 7], cq8, row);
    wkv_step(RB, S, ymx, y, base0 + (size_t)(t + 1) * Cq + row, lane);
  }
  #pragma unroll
  for (int o = 32; o; o >>= 1) ymx = fmaxf(ymx, __shfl_xor(ymx, o));
  if (lane == 0) atomicMax(ymax, __float_as_uint(ymx));
}

// ---------------- groupnorm + bonus + gate ----------------
__global__ __launch_bounds__(256) void k_epi1(const float* __restrict__ y, const float* __restrict__ r,
    const float* __restrict__ k, const float* __restrict__ v, const unsigned short* __restrict__ g,
    const float* __restrict__ lnw, const float* __restrict__ lnb, const float* __restrict__ rk,
    unsigned short* __restrict__ yg) {
  int wid = threadIdx.x >> 6, lane = threadIdx.x & 63;
  int idx = blockIdx.x * 4 + wid;
  size_t off = (size_t)idx * 64 + lane;
  int c = ((idx & (Hq - 1)) << 6) | lane;
  float yv = y[off];
  float s = yv;
  #pragma unroll
  for (int o = 32; o; o >>= 1) s += __shfl_xor(s, o);
  float mu = s * (1.f / 64.f);
  float d = yv - mu;
  float vs = d * d;
  #pragma unroll
  for (int o = 32; o; o >>= 1) vs += __shfl_xor(vs, o);
  float yn = d / sqrtf(vs * (1.f / 64.f) + 6.4e-4f);
  float yo = yn * lnw[c] + lnb[c];
  float bon = r[off] * k[off] * rk[c];
  #pragma unroll
  for (int o = 32; o; o >>= 1) bon += __shfl_xor(bon, o);
  yo += bon * v[off];
  yg[off] = f2bu(yo * b2f(g[off]));
}

// ---------------- v_first output ----------------
__global__ void k_vout(const float* __restrict__ vf, const unsigned int* __restrict__ sc,
                       float* __restrict__ out) {
  int i = blockIdx.x * 256 + threadIdx.x;
  if (i >= ELq) return;
  float s = (__uint_as_float(sc[3]) > 179.2f) ? 0.5f : 1.f;
  out[i] = vf[i] * s;
}

extern "C" void kernel_launch(void* const* d_in, const int* in_sizes, int n_in,
                              void* d_out, int out_size, void* d_ws, size_t ws_size,
                              hipStream_t stream) {
  const float* x      = (const float*)d_in[0];
  const float* vfirst = (const float*)d_in[1];
  const float* x_r = (const float*)d_in[2];
  const float* x_w = (const float*)d_in[3];
  const float* x_k = (const float*)d_in[4];
  const float* x_v = (const float*)d_in[5];
  const float* x_a = (const float*)d_in[6];
  const float* x_g = (const float*)d_in[7];
  const float* w0 = (const float*)d_in[8];
  const float* w1 = (const float*)d_in[9];
  const float* w2 = (const float*)d_in[10];
  const float* a0 = (const float*)d_in[11];
  const float* a1 = (const float*)d_in[12];
  const float* a2 = (const float*)d_in[13];
  const float* v0 = (const float*)d_in[14];
  const float* v1 = (const float*)d_in[15];
  const float* v2 = (const float*)d_in[16];
  const float* g1 = (const float*)d_in[17];
  const float* g2 = (const float*)d_in[18];
  const float* k_k = (const float*)d_in[19];
  const float* k_a = (const float*)d_in[20];
  const float* r_k = (const float*)d_in[21];
  const float* W_r = (const float*)d_in[22];
  const float* W_k = (const float*)d_in[23];
  const float* W_v = (const float*)d_in[24];
  const float* W_o = (const float*)d_in[25];
  const float* lnw = (const float*)d_in[26];
  const float* lnb = (const float*)d_in[27];

  char* ws = (char*)d_ws;
  size_t off = 0;
  auto alloc = [&](size_t bytes) -> void* {
    void* p = ws + off; off += (bytes + 255) & ~(size_t)255; return p;
  };
  unsigned int* scal = (unsigned int*)alloc(256);      // [M1, MZ, MVD, MY]
  float* kbuf  = (float*)alloc((size_t)ELq * 4);
  float* vbuf  = (float*)alloc((size_t)ELq * 4);
  float* wbuf  = (float*)alloc((size_t)ELq * 4);
  float* abuf  = (float*)alloc((size_t)ELq * 4);
  float* kkbuf = (float*)alloc((size_t)ELq * 4);
  float* ybuf  = (float*)alloc((size_t)ELq * 4);
  unsigned short* xrb = (unsigned short*)alloc((size_t)ELq * 2);
  unsigned short* xwb = (unsigned short*)alloc((size_t)ELq * 2);
  unsigned short* xkb = (unsigned short*)alloc((size_t)ELq * 2);
  unsigned short* xvb = (unsigned short*)alloc((size_t)ELq * 2);
  unsigned short* xab = (unsigned short*)alloc((size_t)ELq * 2);
  unsigned short* xgb = (unsigned short*)alloc((size_t)ELq * 2);
  unsigned short* gbuf = (unsigned short*)alloc((size_t)ELq * 2);
  unsigned short* ygb  = (unsigned short*)alloc((size_t)ELq * 2);
  unsigned short* WrB = (unsigned short*)alloc((size_t)ELq * 2);
  unsigned short* WkB = (unsigned short*)alloc((size_t)ELq * 2);
  unsigned short* WvB = (unsigned short*)alloc((size_t)ELq * 2);
  unsigned short* WoB = (unsigned short*)alloc((size_t)ELq * 2);
  unsigned short* w1T = (unsigned short*)alloc(64 * 2048 * 2);
  unsigned short* a1T = (unsigned short*)alloc(64 * 2048 * 2);
  unsigned short* v1T = (unsigned short*)alloc(32 * 2048 * 2);
  unsigned short* g1T = (unsigned short*)alloc(128 * 2048 * 2);
  unsigned short* w2T = (unsigned short*)alloc(2048 * 64 * 2);
  unsigned short* a2T = (unsigned short*)alloc(2048 * 64 * 2);
  unsigned short* v2T = (unsigned short*)alloc(2048 * 32 * 2);
  unsigned short* g2T = (unsigned short*)alloc(2048 * 128 * 2);
  unsigned short* hwb = (unsigned short*)alloc((size_t)Mq * 64 * 2);
  unsigned short* hab = (unsigned short*)alloc((size_t)Mq * 64 * 2);
  unsigned short* hvb = (unsigned short*)alloc((size_t)Mq * 32 * 2);
  unsigned short* hgb = (unsigned short*)alloc((size_t)Mq * 128 * 2);
  // d_out doubles as scratch: r in first half (dead before final GEMM writes y there),
  // z in second half (dead before k_vout writes v_first_out there).
  float* rbuf = (float*)d_out;
  float* zbuf = (float*)d_out + ELq;
  float* yout = (float*)d_out;
  float* vfout = (float*)d_out + ELq;

  k_zero<<<1, 64, 0, stream>>>(scal);

  ConvJobs cj;
  cj.j[0]  = {W_r, WrB, Cq, Cq, 0};
  cj.j[1]  = {W_k, WkB, Cq, Cq, 0};
  cj.j[2]  = {W_v, WvB, Cq, Cq, 0};
  cj.j[3]  = {W_o, WoB, Cq, Cq, 0};
  cj.j[4]  = {w1, w1T, 2048, 64, 1};
  cj.j[5]  = {a1, a1T, 2048, 64, 1};
  cj.j[6]  = {v1, v1T, 2048, 32, 1};
  cj.j[7]  = {g1, g1T, 2048, 128, 1};
  cj.j[8]  = {w2, w2T, 64, 2048, 1};
  cj.j[9]  = {a2, a2T, 64, 2048, 1};
  cj.j[10] = {v2, v2T, 32, 2048, 1};
  cj.j[11] = {g2, g2T, 128, 2048, 1};
  k_conv<<<dim3(1024, 1, 12), 256, 0, stream>>>(cj);

  k_prologue<<<ELq / 256, 256, 0, stream>>>(x, x_r, x_w, x_k, x_v, x_a, x_g,
                                            xrb, xwb, xkb, xvb, xab, xgb);

  GJobs g1j;
  g1j.j[0] = {xrb, WrB, nullptr, rbuf, nullptr, nullptr, nullptr, 2048, 0};
  g1j.j[1] = {xkb, WkB, nullptr, kbuf, nullptr, nullptr, nullptr, 2048, 0};
  g1j.j[2] = {xvb, WvB, nullptr, vbuf, nullptr, nullptr, nullptr, 2048, 0};
  g1j.j[3] = g1j.j[0];
  k_gemm128<<<dim3(16, 16, 3), 256, 0, stream>>>(g1j);

  GJob jw = {xwb, w1T, nullptr, nullptr, hwb, nullptr, nullptr, 2048, 3};
  k_gemmN<64><<<16, 256, 0, stream>>>(jw);
  GJob ja = {xab, a1T, nullptr, nullptr, hab, nullptr, nullptr, 2048, 4};
  k_gemmN<64><<<16, 256, 0, stream>>>(ja);
  GJob jv = {xvb, v1T, nullptr, nullptr, hvb, scal + 0, nullptr, 2048, 6};
  k_gemmN<32><<<16, 256, 0, stream>>>(jv);
  GJob jg = {xgb, g1T, nullptr, nullptr, hgb, nullptr, nullptr, 2048, 5};
  k_gemmN<128><<<16, 256, 0, stream>>>(jg);

  GJobs g3j;
  g3j.j[0] = {hwb, w2T, w0, wbuf, nullptr, nullptr, nullptr, 64, 1};
  g3j.j[1] = {hab, a2T, a0, abuf, nullptr, nullptr, nullptr, 64, 2};
  g3j.j[2] = {hvb, v2T, nullptr, zbuf, nullptr, scal + 1, nullptr, 32, 7};
  g3j.j[3] = {hgb, g2T, nullptr, nullptr, gbuf, nullptr, nullptr, 128, 4};
  k_gemm128<<<dim3(16, 16, 4), 256, 0, stream>>>(g3j);

  k_absmax_diff<<<1024, 256, 0, stream>>>(vfirst, vbuf, scal + 2);
  k_vfin<<<ELq / 256, 256, 0, stream>>>(vbuf, vfirst, zbuf, v0, scal);
  k_prep<<<(2 * Tq * Hq) / 4, 256, 0, stream>>>(kbuf, wbuf, abuf, kkbuf, k_k, k_a);
  k_wkv<<<8 * 2 * Hq, 64, 0, stream>>>(rbuf, wbuf, kbuf, vbuf, kkbuf, abuf, ybuf, scal + 3);
  k_epi1<<<(2 * Tq * Hq) / 4, 256, 0, stream>>>(ybuf, rbuf, kbuf, vbuf, gbuf, lnw, lnb, r_k, ygb);

  GJobs gfj;
  gfj.j[0] = {ygb, WoB, nullptr, yout, nullptr, nullptr, scal + 3, 2048, 8};
  gfj.j[1] = gfj.j[0]; gfj.j[2] = gfj.j[0]; gfj.j[3] = gfj.j[0];
  k_gemm128<<<dim3(16, 16, 1), 256, 0, stream>>>(gfj);

  k_vout<<<ELq / 256, 256, 0, stream>>>(vfirst, scal, vfout);
}

// Round 4
// 717.728 us; speedup vs baseline: 1.9804x; 1.4078x over previous
//
#include <hip/hip_runtime.h>
#include <hip/hip_bf16.h>

#define ELq 4194304   // B*T*C
#define Cq 2048
#define Tq 1024
#define Hq 32
#define Mq 2048       // B*T

typedef __attribute__((ext_vector_type(8))) short bf16x8;
typedef __attribute__((ext_vector_type(4))) float f32x4;

__device__ __forceinline__ unsigned short f2bu(float f) {
  union { float f; unsigned u; } v; v.f = f;
  unsigned r = v.u + 0x7fffu + ((v.u >> 16) & 1u);
  return (unsigned short)(r >> 16);
}
__device__ __forceinline__ float b2f(unsigned short u) {
  union { unsigned u; float f; } v; v.u = ((unsigned)u) << 16;
  return v.f;
}
__device__ __forceinline__ void gl_lds16(const void* g, void* l) {
  __builtin_amdgcn_global_load_lds((const __attribute__((address_space(1))) unsigned int*)g,
                                   (__attribute__((address_space(3))) unsigned int*)l, 16, 0, 0);
}

// DPP cross-lane add: x + lane-permuted x. VALU-pipe (no LDS), ~4-8 cyc.
template<int CTRL>
__device__ __forceinline__ float dpp_add(float x) {
  int t = __builtin_amdgcn_update_dpp(0, __builtin_bit_cast(int, x), CTRL, 0xF, 0xF, true);
  return x + __builtin_bit_cast(float, t);
}

// ---------------- weight convert / transpose ----------------
struct ConvJob { const float* src; unsigned short* dst; int rows, cols, trans; };
struct ConvJobs { ConvJob j[12]; };

__global__ void k_conv(ConvJobs jobs) {
  ConvJob jb = jobs.j[blockIdx.z];
  int n = jb.rows * jb.cols;
  for (int i = blockIdx.x * blockDim.x + threadIdx.x; i < n; i += gridDim.x * blockDim.x) {
    float v;
    if (jb.trans) {
      int col = i / jb.rows;            // out (cols, rows): out[col][row] = in[row][col]
      int row = i - col * jb.rows;
      v = jb.src[(size_t)row * jb.cols + col];
    } else {
      v = jb.src[i];
    }
    jb.dst[i] = f2bu(v);
  }
}

__global__ void k_zero(unsigned int* p) { if (threadIdx.x < 8) p[threadIdx.x] = 0u; }

// ---------------- token shift prologue ----------------
__global__ void k_prologue(const float* __restrict__ x,
    const float* __restrict__ mr, const float* __restrict__ mw, const float* __restrict__ mk,
    const float* __restrict__ mv, const float* __restrict__ ma, const float* __restrict__ mg,
    unsigned short* __restrict__ xr, unsigned short* __restrict__ xw, unsigned short* __restrict__ xk,
    unsigned short* __restrict__ xv, unsigned short* __restrict__ xa, unsigned short* __restrict__ xg)
{
  int i = blockIdx.x * 256 + threadIdx.x;
  if (i >= ELq) return;
  float xc = x[i];
  int t = (i >> 11) & (Tq - 1);
  float xp = t ? x[i - Cq] : 0.f;
  float dx = xp - xc;
  int c = i & (Cq - 1);
  xr[i] = f2bu(xc + dx * mr[c]);
  xw[i] = f2bu(xc + dx * mw[c]);
  xk[i] = f2bu(xc + dx * mk[c]);
  xv[i] = f2bu(xc + dx * mv[c]);
  xa[i] = f2bu(xc + dx * ma[c]);
  xg[i] = f2bu(xc + dx * mg[c]);
}

// ---------------- GEMM (A MxK row-major bf16, B NxK row-major bf16; C = A*B^T) ----------------
struct GJob {
  const unsigned short* A; const unsigned short* B;
  const float* bias; float* Cf; unsigned short* Cb;
  unsigned int* amax; const unsigned int* flag;
  int K; int epi;
};
struct GJobs { GJob j[4]; };

// epi: 0 f32 | 1 f32+bias | 2 f32 sigmoid(v+bias) | 3 bf16 tanh | 4 bf16 | 5 bf16 sigmoid
//      6 bf16+absmax | 7 f32+absmax | 8 f32*flagscale
__device__ __forceinline__ void epi_store(int epi, float v, size_t o,
    float* Cf, unsigned short* Cb, const float* bias, int col, float scale, float& lmax)
{
  switch (epi) {
    case 0: Cf[o] = v; break;
    case 1: Cf[o] = v + bias[col]; break;
    case 2: Cf[o] = 1.f / (1.f + expf(-(v + bias[col]))); break;
    case 3: Cb[o] = f2bu(tanhf(v)); break;
    case 4: Cb[o] = f2bu(v); break;
    case 5: Cb[o] = f2bu(1.f / (1.f + expf(-v))); break;
    case 6: lmax = fmaxf(lmax, fabsf(v)); Cb[o] = f2bu(v); break;
    case 7: lmax = fmaxf(lmax, fabsf(v)); Cf[o] = v; break;
    case 8: Cf[o] = v * scale; break;
  }
}

__global__ __launch_bounds__(256, 2) void k_gemm128(GJobs jobs) {
  GJob jb = jobs.j[blockIdx.z];
  __shared__ __align__(16) unsigned short As[128 * 32];
  __shared__ __align__(16) unsigned short Bs[128 * 32];
  __shared__ float sred[4];
  const int tid = threadIdx.x, lane = tid & 63, wid = tid >> 6;
  const int wr = wid >> 1, wc = wid & 1;
  const int m0 = blockIdx.y * 128, n0 = blockIdx.x * 128;
  const int K = jb.K;
  const unsigned short* A = jb.A; const unsigned short* B = jb.B;
  f32x4 acc[4][4] = {};
  for (int k0 = 0; k0 < K; k0 += 32) {
    #pragma unroll
    for (int i = 0; i < 2; ++i) {
      int cw = wid * 64 + i * 256;   // wave-uniform chunk base
      int c = cw + lane;
      int row = c >> 2, q = c & 3;
      gl_lds16(A + (size_t)(m0 + row) * K + k0 + q * 8, &As[cw * 8]);
      gl_lds16(B + (size_t)(n0 + row) * K + k0 + q * 8, &Bs[cw * 8]);
    }
    __syncthreads();
    const int kg = (lane >> 4) * 8;
    bf16x8 af[4], bq[4];
    #pragma unroll
    for (int mi = 0; mi < 4; ++mi)
      af[mi] = *(const bf16x8*)&As[(wr * 64 + mi * 16 + (lane & 15)) * 32 + kg];
    #pragma unroll
    for (int ni = 0; ni < 4; ++ni)
      bq[ni] = *(const bf16x8*)&Bs[(wc * 64 + ni * 16 + (lane & 15)) * 32 + kg];
    #pragma unroll
    for (int mi = 0; mi < 4; ++mi)
      #pragma unroll
      for (int ni = 0; ni < 4; ++ni)
        acc[mi][ni] = __builtin_amdgcn_mfma_f32_16x16x32_bf16(af[mi], bq[ni], acc[mi][ni], 0, 0, 0);
    __syncthreads();
  }
  float scale = 1.f;
  if (jb.epi == 8) scale = (__uint_as_float(*jb.flag) > 179.2f) ? 0.5f : 1.f;
  float lmax = 0.f;
  #pragma unroll
  for (int mi = 0; mi < 4; ++mi)
    #pragma unroll
    for (int ni = 0; ni < 4; ++ni) {
      int col = n0 + wc * 64 + ni * 16 + (lane & 15);
      int row = m0 + wr * 64 + mi * 16 + ((lane >> 4) << 2);
      #pragma unroll
      for (int q = 0; q < 4; ++q)
        epi_store(jb.epi, acc[mi][ni][q], (size_t)(row + q) * 2048 + col,
                  jb.Cf, jb.Cb, jb.bias, col, scale, lmax);
    }
  if (jb.epi == 6 || jb.epi == 7) {
    #pragma unroll
    for (int o = 32; o; o >>= 1) lmax = fmaxf(lmax, __shfl_xor(lmax, o));
    if (lane == 0) sred[wid] = lmax;
    __syncthreads();
    if (tid == 0)
      atomicMax(jb.amax, __float_as_uint(fmaxf(fmaxf(sred[0], sred[1]), fmaxf(sred[2], sred[3]))));
  }
}

template<int TBN>
__global__ __launch_bounds__(256, 2) void k_gemmN(GJob jb) {
  __shared__ __align__(16) unsigned short As[128 * 32];
  __shared__ __align__(16) unsigned short Bs[TBN * 32];
  __shared__ float sred[4];
  const int tid = threadIdx.x, lane = tid & 63, wid = tid >> 6;
  const int m0 = blockIdx.x * 128;
  const int K = jb.K;
  constexpr int NF = TBN / 16;
  const unsigned short* A = jb.A; const unsigned short* B = jb.B;
  f32x4 acc[2][NF] = {};
  for (int k0 = 0; k0 < K; k0 += 32) {
    for (int cw = wid * 64; cw < 512; cw += 256) {
      int c = cw + lane; int row = c >> 2, q = c & 3;
      gl_lds16(A + (size_t)(m0 + row) * K + k0 + q * 8, &As[cw * 8]);
    }
    for (int cw = wid * 64; cw < TBN * 4; cw += 256) {
      int c = cw + lane; int row = c >> 2, q = c & 3;
      gl_lds16(B + (size_t)row * K + k0 + q * 8, &Bs[cw * 8]);
    }
    __syncthreads();
    const int kg = (lane >> 4) * 8;
    bf16x8 af[2], bq[NF];
    #pragma unroll
    for (int mi = 0; mi < 2; ++mi)
      af[mi] = *(const bf16x8*)&As[(wid * 32 + mi * 16 + (lane & 15)) * 32 + kg];
    #pragma unroll
    for (int ni = 0; ni < NF; ++ni)
      bq[ni] = *(const bf16x8*)&Bs[(ni * 16 + (lane & 15)) * 32 + kg];
    #pragma unroll
    for (int mi = 0; mi < 2; ++mi)
      #pragma unroll
      for (int ni = 0; ni < NF; ++ni)
        acc[mi][ni] = __builtin_amdgcn_mfma_f32_16x16x32_bf16(af[mi], bq[ni], acc[mi][ni], 0, 0, 0);
    __syncthreads();
  }
  float lmax = 0.f;
  #pragma unroll
  for (int mi = 0; mi < 2; ++mi)
    #pragma unroll
    for (int ni = 0; ni < NF; ++ni) {
      int col = ni * 16 + (lane & 15);
      int row = m0 + wid * 32 + mi * 16 + ((lane >> 4) << 2);
      #pragma unroll
      for (int q = 0; q < 4; ++q)
        epi_store(jb.epi, acc[mi][ni][q], (size_t)(row + q) * TBN + col,
                  jb.Cf, jb.Cb, jb.bias, col, 1.f, lmax);
    }
  if (jb.epi == 6 || jb.epi == 7) {
    #pragma unroll
    for (int o = 32; o; o >>= 1) lmax = fmaxf(lmax, __shfl_xor(lmax, o));
    if (lane == 0) sred[wid] = lmax;
    __syncthreads();
    if (tid == 0)
      atomicMax(jb.amax, __float_as_uint(fmaxf(fmaxf(sred[0], sred[1]), fmaxf(sred[2], sred[3]))));
  }
}

// ---------------- absmax(v_first - v_raw) ----------------
__global__ void k_absmax_diff(const float* __restrict__ a, const float* __restrict__ b, unsigned int* out) {
  float m = 0.f;
  for (int i = blockIdx.x * blockDim.x + threadIdx.x; i < ELq; i += gridDim.x * blockDim.x)
    m = fmaxf(m, fabsf(a[i] - b[i]));
  #pragma unroll
  for (int o = 32; o; o >>= 1) m = fmaxf(m, __shfl_xor(m, o));
  __shared__ float sred[4];
  int lane = threadIdx.x & 63, wid = threadIdx.x >> 6;
  if (lane == 0) sred[wid] = m;
  __syncthreads();
  if (threadIdx.x == 0)
    atomicMax(out, __float_as_uint(fmaxf(fmaxf(sred[0], sred[1]), fmaxf(sred[2], sred[3]))));
}

// ---------------- v residual gating (in place over v_raw) ----------------
__global__ void k_vfin(float* __restrict__ v, const float* __restrict__ vf, const float* __restrict__ z,
                       const float* __restrict__ v0, const unsigned int* __restrict__ sc) {
  int i = blockIdx.x * 256 + threadIdx.x;
  if (i >= ELq) return;
  float m1 = fmaxf(__uint_as_float(sc[0]), 1.f);
  float m2 = fmaxf(__uint_as_float(sc[1]) / m1, 1.f);
  float mvd = fmaxf(__uint_as_float(sc[2]), 1.f);
  int c = i & (Cq - 1);
  float gx = v0[c] + z[i] / (m1 * m2);
  gx = fminf(fmaxf(gx, -16.f), 16.f);
  float gate = 1.f / (1.f + expf(-gx));
  float vr = v[i];
  v[i] = vr + (vf[i] - vr) * (gate / mvd);
}

// ---------------- wkv stream prep: kk-norm, k-final, decay, a/b streams ----------------
__global__ __launch_bounds__(256) void k_prep(float* __restrict__ k, float* __restrict__ w,
    float* __restrict__ asig, float* __restrict__ kkout,
    const float* __restrict__ kkw, const float* __restrict__ kaw) {
  int wid = threadIdx.x >> 6, lane = threadIdx.x & 63;
  int idx = blockIdx.x * 4 + wid;          // (b*T + t)*H + h
  size_t off = (size_t)idx * 64 + lane;
  int c = ((idx & (Hq - 1)) << 6) | lane;  // h*64 + n
  float kr = k[off];
  float kkv = kr * kkw[c];
  float ss = kkv * kkv;
  #pragma unroll
  for (int o = 32; o; o >>= 1) ss += __shfl_xor(ss, o);
  float kkn = kkv / fmaxf(sqrtf(ss), 1e-12f);
  float as = asig[off];
  kkout[off] = -kkn;                       // a-stream
  asig[off] = kkn * as;                    // b-stream (overwrite after read)
  k[off] = kr * (1.f + (as - 1.f) * kaw[c]);
  float wl = w[off];
  float wlog = -log1pf(expf(-wl)) - 0.5f;  // -softplus(-wlog) - 0.5
  w[off] = expf(-expf(wlog));              // decay in (0,1)
}

// ---------------- wkv7 scan: row-parallel, global->VGPR pipelined, DPP reductions ----
// Rows i of S are independent: S_i <- S_i*w + (S_i.a)*b + v_i*k ; y_i = S_i.r
// Block = 8 rows of one head (512 blocks). lane: row = rq*8 + (lane>>3),
// cols [(lane&7)*8, +8). Reductions: 3 DPP adds (xor1, xor2, half_mirror) — VALU pipe.
// Streams load straight global->VGPR, prefetch distance 4 via 4 named buffers
// (static indexing), unroll x4 (1024 = 4*256). Compiler inserts counted vmcnt.
// blockIdx mapping: bh = blk&63 so the 8 row-octet blocks of one head share an XCD/L2.
struct SRg { float4 r0, r1, w0, w1, k0, k1, a0, a1, b0, b1; float v; };

__device__ __forceinline__ void ld_g(SRg& R,
    const float* __restrict__ rS, const float* __restrict__ wS, const float* __restrict__ kS,
    const float* __restrict__ vS, const float* __restrict__ aS, const float* __restrict__ bS,
    size_t sb, int cq8, int row) {
  R.r0 = *(const float4*)(rS + sb + cq8); R.r1 = *(const float4*)(rS + sb + cq8 + 4);
  R.w0 = *(const float4*)(wS + sb + cq8); R.w1 = *(const float4*)(wS + sb + cq8 + 4);
  R.k0 = *(const float4*)(kS + sb + cq8); R.k1 = *(const float4*)(kS + sb + cq8 + 4);
  R.a0 = *(const float4*)(aS + sb + cq8); R.a1 = *(const float4*)(aS + sb + cq8 + 4);
  R.b0 = *(const float4*)(bS + sb + cq8); R.b1 = *(const float4*)(bS + sb + cq8 + 4);
  R.v  = vS[sb + row];
}

__device__ __forceinline__ void wkv_step(const SRg& R, float S[8], float& ymx,
    float* __restrict__ y, size_t yoff, int lane) {
  float sa = (S[0]*R.a0.x + S[1]*R.a0.y) + (S[2]*R.a0.z + S[3]*R.a0.w)
           + (S[4]*R.a1.x + S[5]*R.a1.y) + (S[6]*R.a1.z + S[7]*R.a1.w);
  sa = dpp_add<0xB1>(sa);    // xor 1 (quad_perm [1,0,3,2])
  sa = dpp_add<0x4E>(sa);    // xor 2 (quad_perm [2,3,0,1])
  sa = dpp_add<0x141>(sa);   // row_half_mirror: other quad within 8
  float vi = R.v;
  float s0 = S[0]*R.w0.x + (sa*R.b0.x + vi*R.k0.x);
  float s1 = S[1]*R.w0.y + (sa*R.b0.y + vi*R.k0.y);
  float s2 = S[2]*R.w0.z + (sa*R.b0.z + vi*R.k0.z);
  float s3 = S[3]*R.w0.w + (sa*R.b0.w + vi*R.k0.w);
  float s4 = S[4]*R.w1.x + (sa*R.b1.x + vi*R.k1.x);
  float s5 = S[5]*R.w1.y + (sa*R.b1.y + vi*R.k1.y);
  float s6 = S[6]*R.w1.z + (sa*R.b1.z + vi*R.k1.z);
  float s7 = S[7]*R.w1.w + (sa*R.b1.w + vi*R.k1.w);
  S[0]=s0; S[1]=s1; S[2]=s2; S[3]=s3; S[4]=s4; S[5]=s5; S[6]=s6; S[7]=s7;
  float yp = (s0*R.r0.x + s1*R.r0.y) + (s2*R.r0.z + s3*R.r0.w)
           + (s4*R.r1.x + s5*R.r1.y) + (s6*R.r1.z + s7*R.r1.w);
  yp = dpp_add<0xB1>(yp);
  yp = dpp_add<0x4E>(yp);
  yp = dpp_add<0x141>(yp);
  if ((lane & 7) == 0) {
    y[yoff] = yp;
    ymx = fmaxf(ymx, fabsf(yp));
  }
}

__global__ __launch_bounds__(64, 1) void k_wkv(
    const float* __restrict__ rS, const float* __restrict__ wS, const float* __restrict__ kS,
    const float* __restrict__ vS, const float* __restrict__ aS, const float* __restrict__ bS,
    float* __restrict__ y, unsigned int* __restrict__ ymax) {
  const int lane = threadIdx.x;
  const int bh = blockIdx.x & 63;          // b*32 + h — same-head octets share an XCD
  const int rq = blockIdx.x >> 6;          // row octet
  const int row = rq * 8 + (lane >> 3);
  const int cq8 = (lane & 7) * 8;
  float S[8];
  #pragma unroll
  for (int q = 0; q < 8; ++q) S[q] = 0.f;
  const size_t base0 = (size_t)(bh >> 5) * Tq * Cq + (size_t)(bh & 31) * 64;

  SRg R0, R1, R2, R3;
  ld_g(R0, rS, wS, kS, vS, aS, bS, base0,            cq8, row);
  ld_g(R1, rS, wS, kS, vS, aS, bS, base0 + Cq,       cq8, row);
  ld_g(R2, rS, wS, kS, vS, aS, bS, base0 + 2 * Cq,   cq8, row);
  ld_g(R3, rS, wS, kS, vS, aS, bS, base0 + 3 * Cq,   cq8, row);

  float ymx = 0.f;
  for (int t = 0; t < Tq; t += 4) {
    int t4 = (t + 4 < Tq) ? t + 4 : Tq - 1;
    int t5 = (t + 5 < Tq) ? t + 5 : Tq - 1;
    int t6 = (t + 6 < Tq) ? t + 6 : Tq - 1;
    int t7 = (t + 7 < Tq) ? t + 7 : Tq - 1;
    wkv_step(R0, S, ymx, y, base0 + (size_t)t * Cq + row, lane);
    ld_g(R0, rS, wS, kS, vS, aS, bS, base0 + (size_t)t4 * Cq, cq8, row);
    wkv_step(R1, S, ymx, y, base0 + (size_t)(t + 1) * Cq + row, lane);
    ld_g(R1, rS, wS, kS, vS, aS, bS, base0 + (size_t)t5 * Cq, cq8, row);
    wkv_step(R2, S, ymx, y, base0 + (size_t)(t + 2) * Cq + row, lane);
    ld_g(R2, rS, wS, kS, vS, aS, bS, base0 + (size_t)t6 * Cq, cq8, row);
    wkv_step(R3, S, ymx, y, base0 + (size_t)(t + 3) * Cq + row, lane);
    ld_g(R3, rS, wS, kS, vS, aS, bS, base0 + (size_t)t7 * Cq, cq8, row);
  }
  #pragma unroll
  for (int o = 32; o; o >>= 1) ymx = fmaxf(ymx, __shfl_xor(ymx, o));
  if (lane == 0) atomicMax(ymax, __float_as_uint(ymx));
}

// ---------------- groupnorm + bonus + gate ----------------
__global__ __launch_bounds__(256) void k_epi1(const float* __restrict__ y, const float* __restrict__ r,
    const float* __restrict__ k, const float* __restrict__ v, const unsigned short* __restrict__ g,
    const float* __restrict__ lnw, const float* __restrict__ lnb, const float* __restrict__ rk,
    unsigned short* __restrict__ yg) {
  int wid = threadIdx.x >> 6, lane = threadIdx.x & 63;
  int idx = blockIdx.x * 4 + wid;
  size_t off = (size_t)idx * 64 + lane;
  int c = ((idx & (Hq - 1)) << 6) | lane;
  float yv = y[off];
  float s = yv;
  #pragma unroll
  for (int o = 32; o; o >>= 1) s += __shfl_xor(s, o);
  float mu = s * (1.f / 64.f);
  float d = yv - mu;
  float vs = d * d;
  #pragma unroll
  for (int o = 32; o; o >>= 1) vs += __shfl_xor(vs, o);
  float yn = d / sqrtf(vs * (1.f / 64.f) + 6.4e-4f);
  float yo = yn * lnw[c] + lnb[c];
  float bon = r[off] * k[off] * rk[c];
  #pragma unroll
  for (int o = 32; o; o >>= 1) bon += __shfl_xor(bon, o);
  yo += bon * v[off];
  yg[off] = f2bu(yo * b2f(g[off]));
}

// ---------------- v_first output ----------------
__global__ void k_vout(const float* __restrict__ vf, const unsigned int* __restrict__ sc,
                       float* __restrict__ out) {
  int i = blockIdx.x * 256 + threadIdx.x;
  if (i >= ELq) return;
  float s = (__uint_as_float(sc[3]) > 179.2f) ? 0.5f : 1.f;
  out[i] = vf[i] * s;
}

extern "C" void kernel_launch(void* const* d_in, const int* in_sizes, int n_in,
                              void* d_out, int out_size, void* d_ws, size_t ws_size,
                              hipStream_t stream) {
  const float* x      = (const float*)d_in[0];
  const float* vfirst = (const float*)d_in[1];
  const float* x_r = (const float*)d_in[2];
  const float* x_w = (const float*)d_in[3];
  const float* x_k = (const float*)d_in[4];
  const float* x_v = (const float*)d_in[5];
  const float* x_a = (const float*)d_in[6];
  const float* x_g = (const float*)d_in[7];
  const float* w0 = (const float*)d_in[8];
  const float* w1 = (const float*)d_in[9];
  const float* w2 = (const float*)d_in[10];
  const float* a0 = (const float*)d_in[11];
  const float* a1 = (const float*)d_in[12];
  const float* a2 = (const float*)d_in[13];
  const float* v0 = (const float*)d_in[14];
  const float* v1 = (const float*)d_in[15];
  const float* v2 = (const float*)d_in[16];
  const float* g1 = (const float*)d_in[17];
  const float* g2 = (const float*)d_in[18];
  const float* k_k = (const float*)d_in[19];
  const float* k_a = (const float*)d_in[20];
  const float* r_k = (const float*)d_in[21];
  const float* W_r = (const float*)d_in[22];
  const float* W_k = (const float*)d_in[23];
  const float* W_v = (const float*)d_in[24];
  const float* W_o = (const float*)d_in[25];
  const float* lnw = (const float*)d_in[26];
  const float* lnb = (const float*)d_in[27];

  char* ws = (char*)d_ws;
  size_t off = 0;
  auto alloc = [&](size_t bytes) -> void* {
    void* p = ws + off; off += (bytes + 255) & ~(size_t)255; return p;
  };
  unsigned int* scal = (unsigned int*)alloc(256);      // [M1, MZ, MVD, MY]
  float* kbuf  = (float*)alloc((size_t)ELq * 4);
  float* vbuf  = (float*)alloc((size_t)ELq * 4);
  float* wbuf  = (float*)alloc((size_t)ELq * 4);
  float* abuf  = (float*)alloc((size_t)ELq * 4);
  float* kkbuf = (float*)alloc((size_t)ELq * 4);
  float* ybuf  = (float*)alloc((size_t)ELq * 4);
  unsigned short* xrb = (unsigned short*)alloc((size_t)ELq * 2);
  unsigned short* xwb = (unsigned short*)alloc((size_t)ELq * 2);
  unsigned short* xkb = (unsigned short*)alloc((size_t)ELq * 2);
  unsigned short* xvb = (unsigned short*)alloc((size_t)ELq * 2);
  unsigned short* xab = (unsigned short*)alloc((size_t)ELq * 2);
  unsigned short* xgb = (unsigned short*)alloc((size_t)ELq * 2);
  unsigned short* gbuf = (unsigned short*)alloc((size_t)ELq * 2);
  unsigned short* ygb  = (unsigned short*)alloc((size_t)ELq * 2);
  unsigned short* WrB = (unsigned short*)alloc((size_t)ELq * 2);
  unsigned short* WkB = (unsigned short*)alloc((size_t)ELq * 2);
  unsigned short* WvB = (unsigned short*)alloc((size_t)ELq * 2);
  unsigned short* WoB = (unsigned short*)alloc((size_t)ELq * 2);
  unsigned short* w1T = (unsigned short*)alloc(64 * 2048 * 2);
  unsigned short* a1T = (unsigned short*)alloc(64 * 2048 * 2);
  unsigned short* v1T = (unsigned short*)alloc(32 * 2048 * 2);
  unsigned short* g1T = (unsigned short*)alloc(128 * 2048 * 2);
  unsigned short* w2T = (unsigned short*)alloc(2048 * 64 * 2);
  unsigned short* a2T = (unsigned short*)alloc(2048 * 64 * 2);
  unsigned short* v2T = (unsigned short*)alloc(2048 * 32 * 2);
  unsigned short* g2T = (unsigned short*)alloc(2048 * 128 * 2);
  unsigned short* hwb = (unsigned short*)alloc((size_t)Mq * 64 * 2);
  unsigned short* hab = (unsigned short*)alloc((size_t)Mq * 64 * 2);
  unsigned short* hvb = (unsigned short*)alloc((size_t)Mq * 32 * 2);
  unsigned short* hgb = (unsigned short*)alloc((size_t)Mq * 128 * 2);
  // d_out doubles as scratch: r in first half (dead before final GEMM writes y there),
  // z in second half (dead before k_vout writes v_first_out there).
  float* rbuf = (float*)d_out;
  float* zbuf = (float*)d_out + ELq;
  float* yout = (float*)d_out;
  float* vfout = (float*)d_out + ELq;

  k_zero<<<1, 64, 0, stream>>>(scal);

  ConvJobs cj;
  cj.j[0]  = {W_r, WrB, Cq, Cq, 0};
  cj.j[1]  = {W_k, WkB, Cq, Cq, 0};
  cj.j[2]  = {W_v, WvB, Cq, Cq, 0};
  cj.j[3]  = {W_o, WoB, Cq, Cq, 0};
  cj.j[4]  = {w1, w1T, 2048, 64, 1};
  cj.j[5]  = {a1, a1T, 2048, 64, 1};
  cj.j[6]  = {v1, v1T, 2048, 32, 1};
  cj.j[7]  = {g1, g1T, 2048, 128, 1};
  cj.j[8]  = {w2, w2T, 64, 2048, 1};
  cj.j[9]  = {a2, a2T, 64, 2048, 1};
  cj.j[10] = {v2, v2T, 32, 2048, 1};
  cj.j[11] = {g2, g2T, 128, 2048, 1};
  k_conv<<<dim3(1024, 1, 12), 256, 0, stream>>>(cj);

  k_prologue<<<ELq / 256, 256, 0, stream>>>(x, x_r, x_w, x_k, x_v, x_a, x_g,
                                            xrb, xwb, xkb, xvb, xab, xgb);

  GJobs g1j;
  g1j.j[0] = {xrb, WrB, nullptr, rbuf, nullptr, nullptr, nullptr, 2048, 0};
  g1j.j[1] = {xkb, WkB, nullptr, kbuf, nullptr, nullptr, nullptr, 2048, 0};
  g1j.j[2] = {xvb, WvB, nullptr, vbuf, nullptr, nullptr, nullptr, 2048, 0};
  g1j.j[3] = g1j.j[0];
  k_gemm128<<<dim3(16, 16, 3), 256, 0, stream>>>(g1j);

  GJob jw = {xwb, w1T, nullptr, nullptr, hwb, nullptr, nullptr, 2048, 3};
  k_gemmN<64><<<16, 256, 0, stream>>>(jw);
  GJob ja = {xab, a1T, nullptr, nullptr, hab, nullptr, nullptr, 2048, 4};
  k_gemmN<64><<<16, 256, 0, stream>>>(ja);
  GJob jv = {xvb, v1T, nullptr, nullptr, hvb, scal + 0, nullptr, 2048, 6};
  k_gemmN<32><<<16, 256, 0, stream>>>(jv);
  GJob jg = {xgb, g1T, nullptr, nullptr, hgb, nullptr, nullptr, 2048, 5};
  k_gemmN<128><<<16, 256, 0, stream>>>(jg);

  GJobs g3j;
  g3j.j[0] = {hwb, w2T, w0, wbuf, nullptr, nullptr, nullptr, 64, 1};
  g3j.j[1] = {hab, a2T, a0, abuf, nullptr, nullptr, nullptr, 64, 2};
  g3j.j[2] = {hvb, v2T, nullptr, zbuf, nullptr, scal + 1, nullptr, 32, 7};
  g3j.j[3] = {hgb, g2T, nullptr, nullptr, gbuf, nullptr, nullptr, 128, 4};
  k_gemm128<<<dim3(16, 16, 4), 256, 0, stream>>>(g3j);

  k_absmax_diff<<<1024, 256, 0, stream>>>(vfirst, vbuf, scal + 2);
  k_vfin<<<ELq / 256, 256, 0, stream>>>(vbuf, vfirst, zbuf, v0, scal);
  k_prep<<<(2 * Tq * Hq) / 4, 256, 0, stream>>>(kbuf, wbuf, abuf, kkbuf, k_k, k_a);
  k_wkv<<<8 * 2 * Hq, 64, 0, stream>>>(rbuf, wbuf, kbuf, vbuf, kkbuf, abuf, ybuf, scal + 3);
  k_epi1<<<(2 * Tq * Hq) / 4, 256, 0, stream>>>(ybuf, rbuf, kbuf, vbuf, gbuf, lnw, lnb, r_k, ygb);

  GJobs gfj;
  gfj.j[0] = {ygb, WoB, nullptr, yout, nullptr, nullptr, scal + 3, 2048, 8};
  gfj.j[1] = gfj.j[0]; gfj.j[2] = gfj.j[0]; gfj.j[3] = gfj.j[0];
  k_gemm128<<<dim3(16, 16, 1), 256, 0, stream>>>(gfj);

  k_vout<<<ELq / 256, 256, 0, stream>>>(vfirst, scal, vfout);
}

// Round 5
// 531.702 us; speedup vs baseline: 2.6733x; 1.3499x over previous
//
#include <hip/hip_runtime.h>
#include <hip/hip_bf16.h>

#define ELq 4194304   // B*T*C
#define Cq 2048
#define Tq 1024
#define Hq 32
#define Mq 2048       // B*T

typedef __attribute__((ext_vector_type(8))) short bf16x8;
typedef __attribute__((ext_vector_type(4))) float f32x4;

__device__ __forceinline__ unsigned short f2bu(float f) {
  union { float f; unsigned u; } v; v.f = f;
  unsigned r = v.u + 0x7fffu + ((v.u >> 16) & 1u);
  return (unsigned short)(r >> 16);
}
__device__ __forceinline__ float b2f(unsigned short u) {
  union { unsigned u; float f; } v; v.u = ((unsigned)u) << 16;
  return v.f;
}
__device__ __forceinline__ void gl_lds16(const void* g, void* l) {
  __builtin_amdgcn_global_load_lds((const __attribute__((address_space(1))) unsigned int*)g,
                                   (__attribute__((address_space(3))) unsigned int*)l, 16, 0, 0);
}

// DPP cross-lane add: x + lane-permuted x. VALU-pipe (no LDS), ~4-8 cyc.
template<int CTRL>
__device__ __forceinline__ float dpp_add(float x) {
  int t = __builtin_amdgcn_update_dpp(0, __builtin_bit_cast(int, x), CTRL, 0xF, 0xF, true);
  return x + __builtin_bit_cast(float, t);
}

// ---------------- weight convert / transpose ----------------
struct ConvJob { const float* src; unsigned short* dst; int rows, cols, trans; };
struct ConvJobs { ConvJob j[12]; };

__global__ void k_conv(ConvJobs jobs) {
  ConvJob jb = jobs.j[blockIdx.z];
  int n = jb.rows * jb.cols;
  if (!jb.trans) {
    int n4 = n >> 2;
    for (int i = blockIdx.x * blockDim.x + threadIdx.x; i < n4; i += gridDim.x * blockDim.x) {
      float4 v = ((const float4*)jb.src)[i];
      ushort4 o;
      o.x = f2bu(v.x); o.y = f2bu(v.y); o.z = f2bu(v.z); o.w = f2bu(v.w);
      ((ushort4*)jb.dst)[i] = o;
    }
  } else {
    for (int i = blockIdx.x * blockDim.x + threadIdx.x; i < n; i += gridDim.x * blockDim.x) {
      int col = i / jb.rows;            // out (cols, rows): out[col][row] = in[row][col]
      int row = i - col * jb.rows;
      jb.dst[i] = f2bu(jb.src[(size_t)row * jb.cols + col]);
    }
  }
}

__global__ void k_zero(unsigned int* p) { if (threadIdx.x < 8) p[threadIdx.x] = 0u; }

// ---------------- token shift prologue (float4 vectorized) ----------------
__global__ void k_prologue(const float* __restrict__ x,
    const float* __restrict__ mr, const float* __restrict__ mw, const float* __restrict__ mk,
    const float* __restrict__ mv, const float* __restrict__ ma, const float* __restrict__ mg,
    unsigned short* __restrict__ xr, unsigned short* __restrict__ xw, unsigned short* __restrict__ xk,
    unsigned short* __restrict__ xv, unsigned short* __restrict__ xa, unsigned short* __restrict__ xg)
{
  int i4 = blockIdx.x * 256 + threadIdx.x;
  if (i4 >= ELq / 4) return;
  int i = i4 << 2;
  float4 xc = *(const float4*)(x + i);
  int t = (i >> 11) & (Tq - 1);
  float4 xp = make_float4(0.f, 0.f, 0.f, 0.f);
  if (t) xp = *(const float4*)(x + i - Cq);
  float4 dx = make_float4(xp.x - xc.x, xp.y - xc.y, xp.z - xc.z, xp.w - xc.w);
  int c = i & (Cq - 1);
  auto mix = [&](const float* __restrict__ m, unsigned short* __restrict__ o) {
    float4 mm = *(const float4*)(m + c);
    ushort4 u;
    u.x = f2bu(xc.x + dx.x * mm.x); u.y = f2bu(xc.y + dx.y * mm.y);
    u.z = f2bu(xc.z + dx.z * mm.z); u.w = f2bu(xc.w + dx.w * mm.w);
    *(ushort4*)(o + i) = u;
  };
  mix(mr, xr); mix(mw, xw); mix(mk, xk); mix(mv, xv); mix(ma, xa); mix(mg, xg);
}

// ---------------- GEMM (A MxK row-major bf16, B NxK row-major bf16; C = A*B^T) ----------------
struct GJob {
  const unsigned short* A; const unsigned short* B;
  const float* bias; float* Cf; unsigned short* Cb;
  unsigned int* amax; const float* aux;
  int K; int ld; int epi;
};
struct GJobs { GJob j[4]; };

// epi: 0 f32 | 1 f32+bias | 2 f32 sigmoid(v+bias) | 4 bf16 | 7 f32+absmax | 9 f32+absmax(aux-v)
__device__ __forceinline__ void epi_store(int epi, float v, size_t o,
    float* Cf, unsigned short* Cb, const float* bias, const float* aux, int col, float& lmax)
{
  switch (epi) {
    case 0: Cf[o] = v; break;
    case 1: Cf[o] = v + bias[col]; break;
    case 2: Cf[o] = 1.f / (1.f + expf(-(v + bias[col]))); break;
    case 4: Cb[o] = f2bu(v); break;
    case 7: lmax = fmaxf(lmax, fabsf(v)); Cf[o] = v; break;
    case 9: lmax = fmaxf(lmax, fabsf(aux[o] - v)); Cf[o] = v; break;
  }
}

__global__ __launch_bounds__(256, 2) void k_gemm128(GJobs jobs) {
  GJob jb = jobs.j[blockIdx.z];
  __shared__ __align__(16) unsigned short As[128 * 32];
  __shared__ __align__(16) unsigned short Bs[128 * 32];
  __shared__ float sred[4];
  const int tid = threadIdx.x, lane = tid & 63, wid = tid >> 6;
  const int wr = wid >> 1, wc = wid & 1;
  // bijective XCD swizzle (m204): nwg=256 per z, q=32, r=0
  const int lin = blockIdx.y * 16 + blockIdx.x;
  const int swz = (lin & 7) * 32 + (lin >> 3);
  const int m0 = (swz >> 4) * 128, n0 = (swz & 15) * 128;
  const int K = jb.K, ld = jb.ld;
  const unsigned short* A = jb.A; const unsigned short* B = jb.B;
  f32x4 acc[4][4] = {};
  for (int k0 = 0; k0 < K; k0 += 32) {
    #pragma unroll
    for (int i = 0; i < 2; ++i) {
      int cw = wid * 64 + i * 256;   // wave-uniform chunk base
      int c = cw + lane;
      int row = c >> 2, q = c & 3;
      gl_lds16(A + (size_t)(m0 + row) * ld + k0 + q * 8, &As[cw * 8]);
      gl_lds16(B + (size_t)(n0 + row) * ld + k0 + q * 8, &Bs[cw * 8]);
    }
    __syncthreads();
    const int kg = (lane >> 4) * 8;
    bf16x8 af[4], bq[4];
    #pragma unroll
    for (int mi = 0; mi < 4; ++mi)
      af[mi] = *(const bf16x8*)&As[(wr * 64 + mi * 16 + (lane & 15)) * 32 + kg];
    #pragma unroll
    for (int ni = 0; ni < 4; ++ni)
      bq[ni] = *(const bf16x8*)&Bs[(wc * 64 + ni * 16 + (lane & 15)) * 32 + kg];
    #pragma unroll
    for (int mi = 0; mi < 4; ++mi)
      #pragma unroll
      for (int ni = 0; ni < 4; ++ni)
        acc[mi][ni] = __builtin_amdgcn_mfma_f32_16x16x32_bf16(af[mi], bq[ni], acc[mi][ni], 0, 0, 0);
    __syncthreads();
  }
  float lmax = 0.f;
  #pragma unroll
  for (int mi = 0; mi < 4; ++mi)
    #pragma unroll
    for (int ni = 0; ni < 4; ++ni) {
      int col = n0 + wc * 64 + ni * 16 + (lane & 15);
      int row = m0 + wr * 64 + mi * 16 + ((lane >> 4) << 2);
      #pragma unroll
      for (int q = 0; q < 4; ++q)
        epi_store(jb.epi, acc[mi][ni][q], (size_t)(row + q) * 2048 + col,
                  jb.Cf, jb.Cb, jb.bias, jb.aux, col, lmax);
    }
  if (jb.epi == 7 || jb.epi == 9) {
    #pragma unroll
    for (int o = 32; o; o >>= 1) lmax = fmaxf(lmax, __shfl_xor(lmax, o));
    if (lane == 0) sred[wid] = lmax;
    __syncthreads();
    if (tid == 0)
      atomicMax(jb.amax, __float_as_uint(fmaxf(fmaxf(sred[0], sred[1]), fmaxf(sred[2], sred[3]))));
  }
}

// ---------------- skinny GEMM, split-K x8: partials to f32 ws ----------------
template<int TBN>
__global__ __launch_bounds__(256, 2) void k_gemmN_sk(GJob jb) {
  __shared__ __align__(16) unsigned short As[128 * 32];
  __shared__ __align__(16) unsigned short Bs[TBN * 32];
  const int tid = threadIdx.x, lane = tid & 63, wid = tid >> 6;
  const int m0 = blockIdx.x * 128;
  const int koff = blockIdx.y * 256;
  const int ld = jb.ld;
  constexpr int NF = TBN / 16;
  const unsigned short* A = jb.A + koff;
  const unsigned short* B = jb.B + koff;
  float* out = jb.Cf + (size_t)blockIdx.y * (2048 * TBN);
  f32x4 acc[2][NF] = {};
  for (int k0 = 0; k0 < 256; k0 += 32) {
    for (int cw = wid * 64; cw < 512; cw += 256) {
      int c = cw + lane; int row = c >> 2, q = c & 3;
      gl_lds16(A + (size_t)(m0 + row) * ld + k0 + q * 8, &As[cw * 8]);
    }
    for (int cw = wid * 64; cw < TBN * 4; cw += 256) {
      int c = cw + lane; int row = c >> 2, q = c & 3;
      gl_lds16(B + (size_t)row * ld + k0 + q * 8, &Bs[cw * 8]);
    }
    __syncthreads();
    const int kg = (lane >> 4) * 8;
    bf16x8 af[2], bq[NF];
    #pragma unroll
    for (int mi = 0; mi < 2; ++mi)
      af[mi] = *(const bf16x8*)&As[(wid * 32 + mi * 16 + (lane & 15)) * 32 + kg];
    #pragma unroll
    for (int ni = 0; ni < NF; ++ni)
      bq[ni] = *(const bf16x8*)&Bs[(ni * 16 + (lane & 15)) * 32 + kg];
    #pragma unroll
    for (int mi = 0; mi < 2; ++mi)
      #pragma unroll
      for (int ni = 0; ni < NF; ++ni)
        acc[mi][ni] = __builtin_amdgcn_mfma_f32_16x16x32_bf16(af[mi], bq[ni], acc[mi][ni], 0, 0, 0);
    __syncthreads();
  }
  #pragma unroll
  for (int mi = 0; mi < 2; ++mi)
    #pragma unroll
    for (int ni = 0; ni < NF; ++ni) {
      int col = ni * 16 + (lane & 15);
      int row = m0 + wid * 32 + mi * 16 + ((lane >> 4) << 2);
      #pragma unroll
      for (int q = 0; q < 4; ++q)
        out[(size_t)(row + q) * TBN + col] = acc[mi][ni][q];
    }
}

// ---------------- split-K reduce + activations for the 4 skinny GEMMs ----------------
// layout: w[2048x64] | a[2048x64] | v[2048x32] | g[2048x128], 8 split partials each
__global__ void k_skepi(const float* __restrict__ pw, const float* __restrict__ pa,
                        const float* __restrict__ pv, const float* __restrict__ pg,
                        unsigned short* __restrict__ hw, unsigned short* __restrict__ ha,
                        unsigned short* __restrict__ hv, unsigned short* __restrict__ hg,
                        unsigned int* __restrict__ amax) {
  int i = blockIdx.x * 256 + threadIdx.x;    // 0 .. 589823
  const float* src; unsigned short* dst; int stride, mode, loc;
  if (i < 131072)      { src = pw; dst = hw; stride = 131072; mode = 0; loc = i; }
  else if (i < 262144) { src = pa; dst = ha; stride = 131072; mode = 1; loc = i - 131072; }
  else if (i < 327680) { src = pv; dst = hv; stride = 65536;  mode = 2; loc = i - 262144; }
  else                 { src = pg; dst = hg; stride = 262144; mode = 3; loc = i - 327680; }
  float s = 0.f;
  #pragma unroll
  for (int sp = 0; sp < 8; ++sp) s += src[loc + (size_t)sp * stride];
  float lmax = 0.f, o;
  switch (mode) {
    case 0: o = tanhf(s); break;
    case 1: o = s; break;
    case 2: o = s; lmax = fabsf(s); break;
    default: o = 1.f / (1.f + expf(-s)); break;
  }
  dst[loc] = f2bu(o);
  #pragma unroll
  for (int of = 32; of; of >>= 1) lmax = fmaxf(lmax, __shfl_xor(lmax, of));
  if ((threadIdx.x & 63) == 0 && lmax > 0.f) atomicMax(amax, __float_as_uint(lmax));
}

// ---------------- fused: v residual gating + wkv stream prep ----------------
__global__ __launch_bounds__(256) void k_vprep(float* __restrict__ v, const float* __restrict__ vf,
    const float* __restrict__ z, const float* __restrict__ v0c, const unsigned int* __restrict__ sc,
    float* __restrict__ k, float* __restrict__ w, float* __restrict__ asig, float* __restrict__ kkout,
    const float* __restrict__ kkw, const float* __restrict__ kaw) {
  int wid = threadIdx.x >> 6, lane = threadIdx.x & 63;
  int idx = blockIdx.x * 4 + wid;          // (b*T + t)*H + h
  size_t off = (size_t)idx * 64 + lane;
  int c = ((idx & (Hq - 1)) << 6) | lane;  // h*64 + n
  // v gating (was k_vfin)
  float m1 = fmaxf(__uint_as_float(sc[0]), 1.f);
  float m2 = fmaxf(__uint_as_float(sc[1]) / m1, 1.f);
  float mvd = fmaxf(__uint_as_float(sc[2]), 1.f);
  float gx = v0c[c] + z[off] / (m1 * m2);
  gx = fminf(fmaxf(gx, -16.f), 16.f);
  float gate = 1.f / (1.f + expf(-gx));
  float vr = v[off];
  v[off] = vr + (vf[off] - vr) * (gate / mvd);
  // stream prep (was k_prep)
  float kr = k[off];
  float kkv = kr * kkw[c];
  float ss = kkv * kkv;
  #pragma unroll
  for (int o = 32; o; o >>= 1) ss += __shfl_xor(ss, o);
  float kkn = kkv / fmaxf(sqrtf(ss), 1e-12f);
  float as = asig[off];
  kkout[off] = -kkn;                       // a-stream
  asig[off] = kkn * as;                    // b-stream (overwrite after read)
  k[off] = kr * (1.f + (as - 1.f) * kaw[c]);
  float wl = w[off];
  float wlog = -log1pf(expf(-wl)) - 0.5f;  // -softplus(-wlog) - 0.5
  w[off] = expf(-expf(wlog));              // decay in (0,1)
}

// ---------------- wkv7 scan: row-parallel, global->VGPR pipelined, DPP reductions ----
// (unchanged from round 4)
struct SRg { float4 r0, r1, w0, w1, k0, k1, a0, a1, b0, b1; float v; };

__device__ __forceinline__ void ld_g(SRg& R,
    const float* __restrict__ rS, const float* __restrict__ wS, const float* __restrict__ kS,
    const float* __restrict__ vS, const float* __restrict__ aS, const float* __restrict__ bS,
    size_t sb, int cq8, int row) {
  R.r0 = *(const float4*)(rS + sb + cq8); R.r1 = *(const float4*)(rS + sb + cq8 + 4);
  R.w0 = *(const float4*)(wS + sb + cq8); R.w1 = *(const float4*)(wS + sb + cq8 + 4);
  R.k0 = *(const float4*)(kS + sb + cq8); R.k1 = *(const float4*)(kS + sb + cq8 + 4);
  R.a0 = *(const float4*)(aS + sb + cq8); R.a1 = *(const float4*)(aS + sb + cq8 + 4);
  R.b0 = *(const float4*)(bS + sb + cq8); R.b1 = *(const float4*)(bS + sb + cq8 + 4);
  R.v  = vS[sb + row];
}

__device__ __forceinline__ void wkv_step(const SRg& R, float S[8], float& ymx,
    float* __restrict__ y, size_t yoff, int lane) {
  float sa = (S[0]*R.a0.x + S[1]*R.a0.y) + (S[2]*R.a0.z + S[3]*R.a0.w)
           + (S[4]*R.a1.x + S[5]*R.a1.y) + (S[6]*R.a1.z + S[7]*R.a1.w);
  sa = dpp_add<0xB1>(sa);    // xor 1 (quad_perm [1,0,3,2])
  sa = dpp_add<0x4E>(sa);    // xor 2 (quad_perm [2,3,0,1])
  sa = dpp_add<0x141>(sa);   // row_half_mirror: other quad within 8
  float vi = R.v;
  float s0 = S[0]*R.w0.x + (sa*R.b0.x + vi*R.k0.x);
  float s1 = S[1]*R.w0.y + (sa*R.b0.y + vi*R.k0.y);
  float s2 = S[2]*R.w0.z + (sa*R.b0.z + vi*R.k0.z);
  float s3 = S[3]*R.w0.w + (sa*R.b0.w + vi*R.k0.w);
  float s4 = S[4]*R.w1.x + (sa*R.b1.x + vi*R.k1.x);
  float s5 = S[5]*R.w1.y + (sa*R.b1.y + vi*R.k1.y);
  float s6 = S[6]*R.w1.z + (sa*R.b1.z + vi*R.k1.z);
  float s7 = S[7]*R.w1.w + (sa*R.b1.w + vi*R.k1.w);
  S[0]=s0; S[1]=s1; S[2]=s2; S[3]=s3; S[4]=s4; S[5]=s5; S[6]=s6; S[7]=s7;
  float yp = (s0*R.r0.x + s1*R.r0.y) + (s2*R.r0.z + s3*R.r0.w)
           + (s4*R.r1.x + s5*R.r1.y) + (s6*R.r1.z + s7*R.r1.w);
  yp = dpp_add<0xB1>(yp);
  yp = dpp_add<0x4E>(yp);
  yp = dpp_add<0x141>(yp);
  if ((lane & 7) == 0) {
    y[yoff] = yp;
    ymx = fmaxf(ymx, fabsf(yp));
  }
}

__global__ __launch_bounds__(64, 1) void k_wkv(
    const float* __restrict__ rS, const float* __restrict__ wS, const float* __restrict__ kS,
    const float* __restrict__ vS, const float* __restrict__ aS, const float* __restrict__ bS,
    float* __restrict__ y, unsigned int* __restrict__ ymax) {
  const int lane = threadIdx.x;
  const int bh = blockIdx.x & 63;          // b*32 + h — same-head octets share an XCD
  const int rq = blockIdx.x >> 6;          // row octet
  const int row = rq * 8 + (lane >> 3);
  const int cq8 = (lane & 7) * 8;
  float S[8];
  #pragma unroll
  for (int q = 0; q < 8; ++q) S[q] = 0.f;
  const size_t base0 = (size_t)(bh >> 5) * Tq * Cq + (size_t)(bh & 31) * 64;

  SRg R0, R1, R2, R3;
  ld_g(R0, rS, wS, kS, vS, aS, bS, base0,            cq8, row);
  ld_g(R1, rS, wS, kS, vS, aS, bS, base0 + Cq,       cq8, row);
  ld_g(R2, rS, wS, kS, vS, aS, bS, base0 + 2 * Cq,   cq8, row);
  ld_g(R3, rS, wS, kS, vS, aS, bS, base0 + 3 * Cq,   cq8, row);

  float ymx = 0.f;
  for (int t = 0; t < Tq; t += 4) {
    int t4 = (t + 4 < Tq) ? t + 4 : Tq - 1;
    int t5 = (t + 5 < Tq) ? t + 5 : Tq - 1;
    int t6 = (t + 6 < Tq) ? t + 6 : Tq - 1;
    int t7 = (t + 7 < Tq) ? t + 7 : Tq - 1;
    wkv_step(R0, S, ymx, y, base0 + (size_t)t * Cq + row, lane);
    ld_g(R0, rS, wS, kS, vS, aS, bS, base0 + (size_t)t4 * Cq, cq8, row);
    wkv_step(R1, S, ymx, y, base0 + (size_t)(t + 1) * Cq + row, lane);
    ld_g(R1, rS, wS, kS, vS, aS, bS, base0 + (size_t)t5 * Cq, cq8, row);
    wkv_step(R2, S, ymx, y, base0 + (size_t)(t + 2) * Cq + row, lane);
    ld_g(R2, rS, wS, kS, vS, aS, bS, base0 + (size_t)t6 * Cq, cq8, row);
    wkv_step(R3, S, ymx, y, base0 + (size_t)(t + 3) * Cq + row, lane);
    ld_g(R3, rS, wS, kS, vS, aS, bS, base0 + (size_t)t7 * Cq, cq8, row);
  }
  #pragma unroll
  for (int o = 32; o; o >>= 1) ymx = fmaxf(ymx, __shfl_xor(ymx, o));
  if (lane == 0) atomicMax(ymax, __float_as_uint(ymx));
}

// ---------------- groupnorm + bonus + gate ----------------
__global__ __launch_bounds__(256) void k_epi1(const float* __restrict__ y, const float* __restrict__ r,
    const float* __restrict__ k, const float* __restrict__ v, const unsigned short* __restrict__ g,
    const float* __restrict__ lnw, const float* __restrict__ lnb, const float* __restrict__ rk,
    unsigned short* __restrict__ yg) {
  int wid = threadIdx.x >> 6, lane = threadIdx.x & 63;
  int idx = blockIdx.x * 4 + wid;
  size_t off = (size_t)idx * 64 + lane;
  int c = ((idx & (Hq - 1)) << 6) | lane;
  float yv = y[off];
  float s = yv;
  #pragma unroll
  for (int o = 32; o; o >>= 1) s += __shfl_xor(s, o);
  float mu = s * (1.f / 64.f);
  float d = yv - mu;
  float vs = d * d;
  #pragma unroll
  for (int o = 32; o; o >>= 1) vs += __shfl_xor(vs, o);
  float yn = d / sqrtf(vs * (1.f / 64.f) + 6.4e-4f);
  float yo = yn * lnw[c] + lnb[c];
  float bon = r[off] * k[off] * rk[c];
  #pragma unroll
  for (int o = 32; o; o >>= 1) bon += __shfl_xor(bon, o);
  yo += bon * v[off];
  yg[off] = f2bu(yo * b2f(g[off]));
}

// ---------------- W_o split-K finish: yout = (p0+p1)*scale ----------------
__global__ void k_wo_fin(const float* __restrict__ p0, const float* __restrict__ p1,
                         const unsigned int* __restrict__ sc, float* __restrict__ out) {
  int i = blockIdx.x * 256 + threadIdx.x;
  if (i >= ELq / 4) return;
  float s = (__uint_as_float(sc[3]) > 179.2f) ? 0.5f : 1.f;
  float4 a = ((const float4*)p0)[i];
  float4 b = ((const float4*)p1)[i];
  ((float4*)out)[i] = make_float4((a.x + b.x) * s, (a.y + b.y) * s,
                                  (a.z + b.z) * s, (a.w + b.w) * s);
}

// ---------------- v_first output ----------------
__global__ void k_vout(const float* __restrict__ vf, const unsigned int* __restrict__ sc,
                       float* __restrict__ out) {
  int i = blockIdx.x * 256 + threadIdx.x;
  if (i >= ELq) return;
  float s = (__uint_as_float(sc[3]) > 179.2f) ? 0.5f : 1.f;
  out[i] = vf[i] * s;
}

extern "C" void kernel_launch(void* const* d_in, const int* in_sizes, int n_in,
                              void* d_out, int out_size, void* d_ws, size_t ws_size,
                              hipStream_t stream) {
  const float* x      = (const float*)d_in[0];
  const float* vfirst = (const float*)d_in[1];
  const float* x_r = (const float*)d_in[2];
  const float* x_w = (const float*)d_in[3];
  const float* x_k = (const float*)d_in[4];
  const float* x_v = (const float*)d_in[5];
  const float* x_a = (const float*)d_in[6];
  const float* x_g = (const float*)d_in[7];
  const float* w0 = (const float*)d_in[8];
  const float* w1 = (const float*)d_in[9];
  const float* w2 = (const float*)d_in[10];
  const float* a0 = (const float*)d_in[11];
  const float* a1 = (const float*)d_in[12];
  const float* a2 = (const float*)d_in[13];
  const float* v0 = (const float*)d_in[14];
  const float* v1 = (const float*)d_in[15];
  const float* v2 = (const float*)d_in[16];
  const float* g1 = (const float*)d_in[17];
  const float* g2 = (const float*)d_in[18];
  const float* k_k = (const float*)d_in[19];
  const float* k_a = (const float*)d_in[20];
  const float* r_k = (const float*)d_in[21];
  const float* W_r = (const float*)d_in[22];
  const float* W_k = (const float*)d_in[23];
  const float* W_v = (const float*)d_in[24];
  const float* W_o = (const float*)d_in[25];
  const float* lnw = (const float*)d_in[26];
  const float* lnb = (const float*)d_in[27];

  char* ws = (char*)d_ws;
  size_t off = 0;
  auto alloc = [&](size_t bytes) -> void* {
    void* p = ws + off; off += (bytes + 255) & ~(size_t)255; return p;
  };
  unsigned int* scal = (unsigned int*)alloc(256);      // [M1, MZ, MVD, MY]
  float* kbuf  = (float*)alloc((size_t)ELq * 4);
  float* vbuf  = (float*)alloc((size_t)ELq * 4);
  float* wbuf  = (float*)alloc((size_t)ELq * 4);
  float* abuf  = (float*)alloc((size_t)ELq * 4);
  float* kkbuf = (float*)alloc((size_t)ELq * 4);
  float* ybuf  = (float*)alloc((size_t)ELq * 4);
  unsigned short* xrb = (unsigned short*)alloc((size_t)ELq * 2);
  unsigned short* xwb = (unsigned short*)alloc((size_t)ELq * 2);
  unsigned short* xkb = (unsigned short*)alloc((size_t)ELq * 2);
  unsigned short* xvb = (unsigned short*)alloc((size_t)ELq * 2);
  unsigned short* xab = (unsigned short*)alloc((size_t)ELq * 2);
  unsigned short* xgb = (unsigned short*)alloc((size_t)ELq * 2);
  unsigned short* gbuf = (unsigned short*)alloc((size_t)ELq * 2);
  unsigned short* ygb  = (unsigned short*)alloc((size_t)ELq * 2);
  unsigned short* WrB = (unsigned short*)alloc((size_t)ELq * 2);
  unsigned short* WkB = (unsigned short*)alloc((size_t)ELq * 2);
  unsigned short* WvB = (unsigned short*)alloc((size_t)ELq * 2);
  unsigned short* WoB = (unsigned short*)alloc((size_t)ELq * 2);
  unsigned short* w1T = (unsigned short*)alloc(64 * 2048 * 2);
  unsigned short* a1T = (unsigned short*)alloc(64 * 2048 * 2);
  unsigned short* v1T = (unsigned short*)alloc(32 * 2048 * 2);
  unsigned short* g1T = (unsigned short*)alloc(128 * 2048 * 2);
  unsigned short* w2T = (unsigned short*)alloc(2048 * 64 * 2);
  unsigned short* a2T = (unsigned short*)alloc(2048 * 64 * 2);
  unsigned short* v2T = (unsigned short*)alloc(2048 * 32 * 2);
  unsigned short* g2T = (unsigned short*)alloc(2048 * 128 * 2);
  unsigned short* hwb = (unsigned short*)alloc((size_t)Mq * 64 * 2);
  unsigned short* hab = (unsigned short*)alloc((size_t)Mq * 64 * 2);
  unsigned short* hvb = (unsigned short*)alloc((size_t)Mq * 32 * 2);
  unsigned short* hgb = (unsigned short*)alloc((size_t)Mq * 128 * 2);
  float* pskw = (float*)alloc((size_t)8 * Mq * 64 * 4);
  float* pska = (float*)alloc((size_t)8 * Mq * 64 * 4);
  float* pskv = (float*)alloc((size_t)8 * Mq * 32 * 4);
  float* pskg = (float*)alloc((size_t)8 * Mq * 128 * 4);
  // d_out doubles as scratch: r in first half (dead before k_wo_fin writes y there),
  // z in second half (dead before k_vout writes v_first_out there).
  float* rbuf = (float*)d_out;
  float* zbuf = (float*)d_out + ELq;
  float* yout = (float*)d_out;
  float* vfout = (float*)d_out + ELq;
  // W_o split-K partials alias xrb..xvb (dead by then): 2 x ELq floats = 4 x ELq bf16
  float* pWo0 = (float*)xrb;
  float* pWo1 = pWo0 + ELq;

  k_zero<<<1, 64, 0, stream>>>(scal);

  ConvJobs cj;
  cj.j[0]  = {W_r, WrB, Cq, Cq, 0};
  cj.j[1]  = {W_k, WkB, Cq, Cq, 0};
  cj.j[2]  = {W_v, WvB, Cq, Cq, 0};
  cj.j[3]  = {W_o, WoB, Cq, Cq, 0};
  cj.j[4]  = {w1, w1T, 2048, 64, 1};
  cj.j[5]  = {a1, a1T, 2048, 64, 1};
  cj.j[6]  = {v1, v1T, 2048, 32, 1};
  cj.j[7]  = {g1, g1T, 2048, 128, 1};
  cj.j[8]  = {w2, w2T, 64, 2048, 1};
  cj.j[9]  = {a2, a2T, 64, 2048, 1};
  cj.j[10] = {v2, v2T, 32, 2048, 1};
  cj.j[11] = {g2, g2T, 128, 2048, 1};
  k_conv<<<dim3(1024, 1, 12), 256, 0, stream>>>(cj);

  k_prologue<<<ELq / 1024, 256, 0, stream>>>(x, x_r, x_w, x_k, x_v, x_a, x_g,
                                             xrb, xwb, xkb, xvb, xab, xgb);

  // r/k/v big GEMMs; v job also computes absmax(v_first - v) into scal+2
  GJobs g1j;
  g1j.j[0] = {xrb, WrB, nullptr, rbuf, nullptr, nullptr, nullptr, 2048, 2048, 0};
  g1j.j[1] = {xkb, WkB, nullptr, kbuf, nullptr, nullptr, nullptr, 2048, 2048, 0};
  g1j.j[2] = {xvb, WvB, nullptr, vbuf, nullptr, scal + 2, vfirst, 2048, 2048, 9};
  g1j.j[3] = g1j.j[0];
  k_gemm128<<<dim3(16, 16, 3), 256, 0, stream>>>(g1j);

  // skinny GEMMs: split-K x8 partials, then fused reduce+activation
  GJob jw = {xwb, w1T, nullptr, pskw, nullptr, nullptr, nullptr, 256, 2048, 0};
  k_gemmN_sk<64><<<dim3(16, 8), 256, 0, stream>>>(jw);
  GJob ja = {xab, a1T, nullptr, pska, nullptr, nullptr, nullptr, 256, 2048, 0};
  k_gemmN_sk<64><<<dim3(16, 8), 256, 0, stream>>>(ja);
  GJob jv = {xvb, v1T, nullptr, pskv, nullptr, nullptr, nullptr, 256, 2048, 0};
  k_gemmN_sk<32><<<dim3(16, 8), 256, 0, stream>>>(jv);
  GJob jg = {xgb, g1T, nullptr, pskg, nullptr, nullptr, nullptr, 256, 2048, 0};
  k_gemmN_sk<128><<<dim3(16, 8), 256, 0, stream>>>(jg);
  k_skepi<<<2304, 256, 0, stream>>>(pskw, pska, pskv, pskg, hwb, hab, hvb, hgb, scal + 0);

  GJobs g3j;
  g3j.j[0] = {hwb, w2T, w0, wbuf, nullptr, nullptr, nullptr, 64, 64, 1};
  g3j.j[1] = {hab, a2T, a0, abuf, nullptr, nullptr, nullptr, 64, 64, 2};
  g3j.j[2] = {hvb, v2T, nullptr, zbuf, nullptr, scal + 1, nullptr, 32, 32, 7};
  g3j.j[3] = {hgb, g2T, nullptr, nullptr, gbuf, nullptr, nullptr, 128, 128, 4};
  k_gemm128<<<dim3(16, 16, 4), 256, 0, stream>>>(g3j);

  k_vprep<<<(2 * Tq * Hq) / 4, 256, 0, stream>>>(vbuf, vfirst, zbuf, v0, scal,
                                                 kbuf, wbuf, abuf, kkbuf, k_k, k_a);
  k_wkv<<<8 * 2 * Hq, 64, 0, stream>>>(rbuf, wbuf, kbuf, vbuf, kkbuf, abuf, ybuf, scal + 3);
  k_epi1<<<(2 * Tq * Hq) / 4, 256, 0, stream>>>(ybuf, rbuf, kbuf, vbuf, gbuf, lnw, lnb, r_k, ygb);

  // W_o GEMM: split-K x2 (2 blocks/CU), partials into aliased ws, then finish
  GJobs gfj;
  gfj.j[0] = {ygb, WoB, nullptr, pWo0, nullptr, nullptr, nullptr, 1024, 2048, 0};
  gfj.j[1] = {ygb + 1024, WoB + 1024, nullptr, pWo1, nullptr, nullptr, nullptr, 1024, 2048, 0};
  gfj.j[2] = gfj.j[0]; gfj.j[3] = gfj.j[0];
  k_gemm128<<<dim3(16, 16, 2), 256, 0, stream>>>(gfj);
  k_wo_fin<<<ELq / 1024, 256, 0, stream>>>(pWo0, pWo1, scal, yout);

  k_vout<<<ELq / 256, 256, 0, stream>>>(vfirst, scal, vfout);
}